// Round 2
// baseline (347.285 us; speedup 1.0000x reference)
//
#include <hip/hip_runtime.h>

#define N_NODES 100000
#define N_EDGES 20000
#define NNZ_C   600000
#define D 128

typedef short bf16x8 __attribute__((ext_vector_type(8)));
typedef float f32x4  __attribute__((ext_vector_type(4)));

__device__ __forceinline__ unsigned short f2bf(float f) {
    unsigned int u = __float_as_uint(f);
    u = (u + 0x7fffu + ((u >> 16) & 1u)) >> 16;   // RNE
    return (unsigned short)u;
}
__device__ __forceinline__ float bf2f(unsigned short h) {
    return __uint_as_float((unsigned int)h << 16);
}
// pack two fp32 -> two bf16 (truncation) in one v_perm_b32
__device__ __forceinline__ unsigned int pk_trunc(float lo, float hi) {
    return __builtin_amdgcn_perm(__float_as_uint(hi), __float_as_uint(lo),
                                 0x07060302);
}

// ---------------------------------------------------------------------------
// binning constants: fine buckets, 32 ids per bucket -> aggregation kernels
// counting-sort their own bucket in LDS (no global CSR pass needed).
// Slot positions come from direct global atomics (no LDS histogram): one
// pass over the COO, full-grid occupancy.
// ---------------------------------------------------------------------------
#define NBLK_A 2344           // ceil(600000/256), 1 entry/thread
#define EBW 32                // edges per bucket
#define NBE 625               // 20000/32 (exact)
#define ECAP 1536             // mean 960, sigma ~31 -> +18 sigma
#define NBW 32                // nodes per bucket
#define NBN 3125              // 100000/32 (exact)
#define NCAP 512              // mean 192, sigma ~14 -> +23 sigma

// ---------------------------------------------------------------------------
// Pass A: bucket COO by id-range for BOTH sides, direct atomic slot claim.
// Trailing blocks do the W transposes (fp32 -> bf16, [f][k]).
// ---------------------------------------------------------------------------
__global__ __launch_bounds__(256) void bin_pass(
    const int* __restrict__ nidx, const int* __restrict__ eidx,
    const float* __restrict__ cW, const float* __restrict__ rW,
    unsigned short* __restrict__ wtc, unsigned short* __restrict__ wtr,
    int* __restrict__ bucket_e, int* __restrict__ bucket_n,
    int* __restrict__ gcur_e, int* __restrict__ gcur_n) {
    const int bid = blockIdx.x;
    if (bid >= NBLK_A) {   // W transpose: 8 blocks x 4096 elements
        const int t0 = (bid - NBLK_A) * 4096;
        for (int i = threadIdx.x; i < 4096; i += 256) {
            const int t = t0 + i;
            const int m = t >> 14, idx = t & 16383;
            const int f = idx & 127, k = idx >> 7;
            const float* src = m ? rW : cW;
            unsigned short* dst = m ? wtr : wtc;
            dst[f * D + k] = f2bf(src[k * D + f]);
        }
        return;
    }
    const int j = bid * 256 + threadIdx.x;
    if (j >= NNZ_C) return;
    const int e = eidx[j], n = nidx[j];
    {
        const int b = e >> 5;
        const int pos = atomicAdd(&gcur_e[b], 1);
        if (pos < ECAP) bucket_e[b * ECAP + pos] = ((e & 31) << 17) | n;
    }
    {
        const int b = n >> 5;
        const int pos = atomicAdd(&gcur_n[b], 1);
        if (pos < NCAP) bucket_n[b * NCAP + pos] = ((n & 31) << 15) | e;
    }
}

// ---------------------------------------------------------------------------
// MFMA dual GEMM: weights in registers, x double-buffered in LDS (bf16).
// yb = bf16(x @ cW), resb = bf16(x @ rW)  (bias deferred to node_aggregate)
// ---------------------------------------------------------------------------
#define GT 64
#define XPAD 136
#define NTILES ((N_NODES + GT - 1) / GT)   // 1563

__device__ __forceinline__ void stage_tile(unsigned short* __restrict__ buf,
                                           const float* __restrict__ x,
                                           int tile, int r0, int qp) {
    int n = tile * GT + r0;
    if (n >= N_NODES) n = N_NODES - 1;
    const float* xr = x + (size_t)n * D + qp * 16;
    unsigned short* dst = buf + r0 * XPAD + qp * 16;
#pragma unroll
    for (int u = 0; u < 2; ++u) {
        const float4 a = *(const float4*)(xr + u * 8);
        const float4 c = *(const float4*)(xr + u * 8 + 4);
        uint4 v;
        v.x = pk_trunc(a.x, a.y);
        v.y = pk_trunc(a.z, a.w);
        v.z = pk_trunc(c.x, c.y);
        v.w = pk_trunc(c.z, c.w);
        *(uint4*)(dst + u * 8) = v;
    }
}

__device__ __forceinline__ void compute_tile(
    const unsigned short* __restrict__ buf, const bf16x8 (&A)[2][4],
    int tile, int mat, int fh, int quad, int l16,
    unsigned short* __restrict__ yb, unsigned short* __restrict__ resb) {
    f32x4 acc[4][2] = {};
#pragma unroll
    for (int g = 0; g < 4; ++g)
#pragma unroll
        for (int kc = 0; kc < 4; ++kc) {
            const bf16x8 B = *(const bf16x8*)(buf + (g * 16 + l16) * XPAD +
                                              kc * 32 + quad * 8);
            acc[g][0] = __builtin_amdgcn_mfma_f32_16x16x32_bf16(A[0][kc], B, acc[g][0], 0, 0, 0);
            acc[g][1] = __builtin_amdgcn_mfma_f32_16x16x32_bf16(A[1][kc], B, acc[g][1], 0, 0, 0);
        }
    const int nbase = tile * GT;
    unsigned short* dst = mat ? resb : yb;
#pragma unroll
    for (int g = 0; g < 4; ++g) {
        const int n = nbase + g * 16 + l16;
        if (n >= N_NODES) continue;
#pragma unroll
        for (int ft = 0; ft < 2; ++ft) {
            const int f0 = fh + ft * 16 + quad * 4;
            uint2 v;
            v.x = pk_trunc(acc[g][ft][0], acc[g][ft][1]);
            v.y = pk_trunc(acc[g][ft][2], acc[g][ft][3]);
            *(uint2*)(dst + (size_t)n * D + f0) = v;
        }
    }
}

__global__ __launch_bounds__(512) void mfma_gemm(
    const float* __restrict__ x, const unsigned short* __restrict__ wtc,
    const unsigned short* __restrict__ wtr,
    unsigned short* __restrict__ yb, unsigned short* __restrict__ resb) {
    __shared__ unsigned short xs[2][GT * XPAD];

    const int w    = threadIdx.x >> 6;
    const int lane = threadIdx.x & 63;
    const int quad = lane >> 4;
    const int l16  = lane & 15;
    const int mat  = w & 1;
    const int fh   = (w >> 1) * 32;

    const unsigned short* wsrc = mat ? wtr : wtc;
    bf16x8 A[2][4];
#pragma unroll
    for (int ft = 0; ft < 2; ++ft)
#pragma unroll
        for (int kc = 0; kc < 4; ++kc)
            A[ft][kc] = *(const bf16x8*)(wsrc + (fh + ft * 16 + l16) * D +
                                         kc * 32 + quad * 8);

    const int r0 = threadIdx.x >> 3;
    const int qp = threadIdx.x & 7;
    const int t0 = blockIdx.x * 2;

    stage_tile(xs[0], x, t0, r0, qp);
    __syncthreads();
    stage_tile(xs[1], x, t0 + 1, r0, qp);
    compute_tile(xs[0], A, t0, mat, fh, quad, l16, yb, resb);
    __syncthreads();
    compute_tile(xs[1], A, t0 + 1, mat, fh, quad, l16, yb, resb);
}

// ---------------------------------------------------------------------------
// edge aggregation (fused local sort): block = 32-edge bucket. Counting-sort
// bucket entries by local edge id in LDS, then the proven 16-lane-per-edge
// gather loop.
// ---------------------------------------------------------------------------
__global__ __launch_bounds__(256) void edge_aggregate(
    const int* __restrict__ bucket_e, const int* __restrict__ gcur_e,
    const unsigned short* __restrict__ yb, unsigned short* __restrict__ efb) {
    __shared__ int raw[ECAP];
    __shared__ int srt[ECAP];
    __shared__ int cnt[EBW + 1];
    __shared__ int cur[EBW];
    const int tid = threadIdx.x;
    const int b = blockIdx.x;
    int W = gcur_e[b];
    if (W > ECAP) W = ECAP;
    if (tid < EBW + 1) cnt[tid] = 0;
    __syncthreads();
    const int* src = bucket_e + b * ECAP;
    for (int i = tid; i < W; i += 256) {
        const int p = src[i];
        raw[i] = p;
        atomicAdd(&cnt[p >> 17], 1);
    }
    __syncthreads();
    if (tid < EBW) {        // wave-0 exclusive scan over 32 bins
        const int c = cnt[tid];
        int v = c;
#pragma unroll
        for (int off = 1; off < EBW; off <<= 1) {
            const int t = __shfl_up(v, off);
            if (tid >= off) v += t;
        }
        cnt[tid] = v - c;
        cur[tid] = v - c;
        if (tid == EBW - 1) cnt[EBW] = v;
    }
    __syncthreads();
    for (int i = tid; i < W; i += 256) {
        const int p = raw[i];
        const int pos = atomicAdd(&cur[p >> 17], 1);
        srt[pos] = p & 0x1FFFF;
    }
    __syncthreads();

    const int g = tid >> 4;       // 16 groups, 2 edges each
    const int l = tid & 15;       // lane = 8 cols (16B)
#pragma unroll
    for (int u = 0; u < 2; ++u) {
        const int el = g * 2 + u;
        const int beg = cnt[el], end = cnt[el + 1];
        float acc[8] = {};
        int j = beg;
        for (; j + 4 <= end; j += 4) {
            const int n0 = srt[j], n1 = srt[j + 1];
            const int n2 = srt[j + 2], n3 = srt[j + 3];
            const bf16x8 p0 = *(const bf16x8*)(yb + (size_t)n0 * D + l * 8);
            const bf16x8 p1 = *(const bf16x8*)(yb + (size_t)n1 * D + l * 8);
            const bf16x8 p2 = *(const bf16x8*)(yb + (size_t)n2 * D + l * 8);
            const bf16x8 p3 = *(const bf16x8*)(yb + (size_t)n3 * D + l * 8);
#pragma unroll
            for (int i = 0; i < 8; ++i)
                acc[i] += (bf2f((unsigned short)p0[i]) + bf2f((unsigned short)p1[i]))
                        + (bf2f((unsigned short)p2[i]) + bf2f((unsigned short)p3[i]));
        }
        for (; j < end; ++j) {
            const bf16x8 p = *(const bf16x8*)(yb + (size_t)srt[j] * D + l * 8);
#pragma unroll
            for (int i = 0; i < 8; ++i) acc[i] += bf2f((unsigned short)p[i]);
        }
        const int deg = end - beg;
        const float inv = deg ? 1.f / (float)deg : 0.f;
        bf16x8 o;
#pragma unroll
        for (int i = 0; i < 8; ++i) o[i] = (short)f2bf(acc[i] * inv);
        *(bf16x8*)(efb + (size_t)(b * EBW + el) * D + l * 8) = o;
    }
}

// ---------------------------------------------------------------------------
// node aggregation (fused local sort): block = 32-node bucket. Sort by local
// node id, gather efb rows, epilogue out = resb + acc*inv + rb + cb.
// Sole writer of out (fp32).
// ---------------------------------------------------------------------------
__global__ __launch_bounds__(256) void node_aggregate(
    const int* __restrict__ bucket_n, const int* __restrict__ gcur_n,
    const unsigned short* __restrict__ efb, const unsigned short* __restrict__ resb,
    const float* __restrict__ rb, const float* __restrict__ cb,
    float* __restrict__ out) {
    __shared__ int raw[NCAP];
    __shared__ int srt[NCAP];
    __shared__ int cnt[NBW + 1];
    __shared__ int cur[NBW];
    const int tid = threadIdx.x;
    const int b = blockIdx.x;
    int W = gcur_n[b];
    if (W > NCAP) W = NCAP;
    if (tid < NBW + 1) cnt[tid] = 0;
    __syncthreads();
    const int* src = bucket_n + b * NCAP;
    for (int i = tid; i < W; i += 256) {
        const int p = src[i];
        raw[i] = p;
        atomicAdd(&cnt[p >> 15], 1);
    }
    __syncthreads();
    if (tid < NBW) {
        const int c = cnt[tid];
        int v = c;
#pragma unroll
        for (int off = 1; off < NBW; off <<= 1) {
            const int t = __shfl_up(v, off);
            if (tid >= off) v += t;
        }
        cnt[tid] = v - c;
        cur[tid] = v - c;
        if (tid == NBW - 1) cnt[NBW] = v;
    }
    __syncthreads();
    for (int i = tid; i < W; i += 256) {
        const int p = raw[i];
        const int pos = atomicAdd(&cur[p >> 15], 1);
        srt[pos] = p & 0x7FFF;
    }
    __syncthreads();

    const int g = tid >> 4;       // 16 groups, 2 nodes each
    const int l = tid & 15;
#pragma unroll
    for (int u = 0; u < 2; ++u) {
        const int nl = g * 2 + u;
        const int n = b * NBW + nl;
        const int beg = cnt[nl], end = cnt[nl + 1];
        float acc[8] = {};
        int j = beg;
        for (; j + 2 <= end; j += 2) {
            const int e0 = srt[j], e1 = srt[j + 1];
            const bf16x8 p0 = *(const bf16x8*)(efb + (size_t)e0 * D + l * 8);
            const bf16x8 p1 = *(const bf16x8*)(efb + (size_t)e1 * D + l * 8);
#pragma unroll
            for (int i = 0; i < 8; ++i)
                acc[i] += bf2f((unsigned short)p0[i]) + bf2f((unsigned short)p1[i]);
        }
        if (j < end) {
            const bf16x8 p = *(const bf16x8*)(efb + (size_t)srt[j] * D + l * 8);
#pragma unroll
            for (int i = 0; i < 8; ++i) acc[i] += bf2f((unsigned short)p[i]);
        }
        const int deg = end - beg;
        const float inv = deg ? 1.f / (float)deg : 0.f;
        const bf16x8 r = *(const bf16x8*)(resb + (size_t)n * D + l * 8);
        const float4 rb0 = *(const float4*)(rb + l * 8);
        const float4 rb1 = *(const float4*)(rb + l * 8 + 4);
        const float4 cb0 = *(const float4*)(cb + l * 8);
        const float4 cb1 = *(const float4*)(cb + l * 8 + 4);
        float4 o0, o1;
        o0.x = bf2f((unsigned short)r[0]) + acc[0] * inv + rb0.x + cb0.x;
        o0.y = bf2f((unsigned short)r[1]) + acc[1] * inv + rb0.y + cb0.y;
        o0.z = bf2f((unsigned short)r[2]) + acc[2] * inv + rb0.z + cb0.z;
        o0.w = bf2f((unsigned short)r[3]) + acc[3] * inv + rb0.w + cb0.w;
        o1.x = bf2f((unsigned short)r[4]) + acc[4] * inv + rb1.x + cb1.x;
        o1.y = bf2f((unsigned short)r[5]) + acc[5] * inv + rb1.y + cb1.y;
        o1.z = bf2f((unsigned short)r[6]) + acc[6] * inv + rb1.z + cb1.z;
        o1.w = bf2f((unsigned short)r[7]) + acc[7] * inv + rb1.w + cb1.w;
        const size_t o = (size_t)n * D + l * 8;
        *(float4*)(out + o) = o0;
        *(float4*)(out + o + 4) = o1;
    }
}

// ---------------------------------------------------------------------------
extern "C" void kernel_launch(void* const* d_in, const int* in_sizes, int n_in,
                              void* d_out, int out_size, void* d_ws,
                              size_t ws_size, hipStream_t stream) {
    const float* x  = (const float*)d_in[0];
    const int* nidx = (const int*)d_in[1];
    const int* eidx = (const int*)d_in[2];
    const float* cW = (const float*)d_in[3];
    const float* cb = (const float*)d_in[4];
    const float* rW = (const float*)d_in[5];
    const float* rb = (const float*)d_in[6];
    float* out = (float*)d_out;

    char* ws = (char*)d_ws;
    size_t off = 0;
    auto alloc = [&](size_t bytes) {
        size_t o = off;
        off += (bytes + 255) & ~(size_t)255;
        return o;
    };
    unsigned short* yb   = (unsigned short*)(ws + alloc((size_t)N_NODES * D * 2));
    unsigned short* resb = (unsigned short*)(ws + alloc((size_t)N_NODES * D * 2));
    unsigned short* efb  = (unsigned short*)(ws + alloc((size_t)N_EDGES * D * 2));
    unsigned short* wtc  = (unsigned short*)(ws + alloc((size_t)D * D * 2));
    unsigned short* wtr  = (unsigned short*)(ws + alloc((size_t)D * D * 2));
    int* bucket_e = (int*)(ws + alloc((size_t)NBE * ECAP * 4));
    int* bucket_n = (int*)(ws + alloc((size_t)NBN * NCAP * 4));
    int* gcur     = (int*)(ws + alloc((size_t)(NBE + NBN) * 4));
    int* gcur_e = gcur;
    int* gcur_n = gcur + NBE;

    hipMemsetAsync(gcur, 0, (size_t)(NBE + NBN) * 4, stream);

    // bin_pass also produces wtc/wtr (gemm depends on them)
    bin_pass<<<NBLK_A + 8, 256, 0, stream>>>(nidx, eidx, cW, rW, wtc, wtr,
                                             bucket_e, bucket_n, gcur_e, gcur_n);

    mfma_gemm<<<(NTILES + 1) / 2, 512, 0, stream>>>(x, wtc, wtr, yb, resb);

    edge_aggregate<<<NBE, 256, 0, stream>>>(bucket_e, gcur_e, yb, efb);
    node_aggregate<<<NBN, 256, 0, stream>>>(bucket_n, gcur_n, efb, resb,
                                            rb, cb, out);
}

// Round 3
// 244.024 us; speedup vs baseline: 1.4232x; 1.4232x over previous
//
#include <hip/hip_runtime.h>

#define N_NODES 100000
#define N_EDGES 20000
#define NNZ_C   600000
#define D 128

typedef short bf16x8 __attribute__((ext_vector_type(8)));
typedef float f32x4  __attribute__((ext_vector_type(4)));

__device__ __forceinline__ unsigned short f2bf(float f) {
    unsigned int u = __float_as_uint(f);
    u = (u + 0x7fffu + ((u >> 16) & 1u)) >> 16;   // RNE
    return (unsigned short)u;
}
__device__ __forceinline__ float bf2f(unsigned short h) {
    return __uint_as_float((unsigned int)h << 16);
}
// pack two fp32 -> two bf16 (truncation) in one v_perm_b32
__device__ __forceinline__ unsigned int pk_trunc(float lo, float hi) {
    return __builtin_amdgcn_perm(__float_as_uint(hi), __float_as_uint(lo),
                                 0x07060302);
}

// ---------------------------------------------------------------------------
// binning constants: fine buckets (32 ids each). Slot claim = direct global
// atomicAdd, but every counter PADDED to its own 128B line (atomic RMW
// serialization is line-granular), and edge buckets split into 4 segments
// to shorten the per-counter serial chain (960 -> 240 increments).
// ---------------------------------------------------------------------------
#define NBLK_A 2344           // ceil(600000/256), 1 entry/thread
#define EBW 32                // edges per bucket
#define NBE 625               // 20000/32 (exact)
#define SEG_E 4               // counter segments per edge bucket
#define ECAP_SEG 384          // per-seg cap: mean 240, sigma 15.5 -> +9.3σ
#define NBW 32                // nodes per bucket
#define NBN 3125              // 100000/32 (exact)
#define NCAP 512              // mean 192, sigma ~14 -> +23σ
#define PADI 32               // ints per counter line (128 B)
#define GCUR_INTS ((NBE * SEG_E + NBN) * PADI)

// ---------------------------------------------------------------------------
// Pass A: bucket COO by id-range for BOTH sides, direct atomic slot claim on
// line-padded counters. Trailing blocks do the W transposes (fp32->bf16).
// ---------------------------------------------------------------------------
__global__ __launch_bounds__(256) void bin_pass(
    const int* __restrict__ nidx, const int* __restrict__ eidx,
    const float* __restrict__ cW, const float* __restrict__ rW,
    unsigned short* __restrict__ wtc, unsigned short* __restrict__ wtr,
    int* __restrict__ bucket_e, int* __restrict__ bucket_n,
    int* __restrict__ gcur_e, int* __restrict__ gcur_n) {
    const int bid = blockIdx.x;
    if (bid >= NBLK_A) {   // W transpose: 8 blocks x 4096 elements
        const int t0 = (bid - NBLK_A) * 4096;
        for (int i = threadIdx.x; i < 4096; i += 256) {
            const int t = t0 + i;
            const int m = t >> 14, idx = t & 16383;
            const int f = idx & 127, k = idx >> 7;
            const float* src = m ? rW : cW;
            unsigned short* dst = m ? wtr : wtc;
            dst[f * D + k] = f2bf(src[k * D + f]);
        }
        return;
    }
    const int j = bid * 256 + threadIdx.x;
    if (j >= NNZ_C) return;
    const int e = eidx[j], n = nidx[j];
    {
        const int seg = (e >> 5) * SEG_E + (j & (SEG_E - 1));
        const int pos = atomicAdd(&gcur_e[seg * PADI], 1);
        if (pos < ECAP_SEG) bucket_e[seg * ECAP_SEG + pos] = ((e & 31) << 17) | n;
    }
    {
        const int b = n >> 5;
        const int pos = atomicAdd(&gcur_n[b * PADI], 1);
        if (pos < NCAP) bucket_n[b * NCAP + pos] = ((n & 31) << 15) | e;
    }
}

// ---------------------------------------------------------------------------
// MFMA dual GEMM: weights in registers, x double-buffered in LDS (bf16).
// yb = bf16(x @ cW), resb = bf16(x @ rW)  (bias deferred to node_aggregate)
// ---------------------------------------------------------------------------
#define GT 64
#define XPAD 136
#define NTILES ((N_NODES + GT - 1) / GT)   // 1563

__device__ __forceinline__ void stage_tile(unsigned short* __restrict__ buf,
                                           const float* __restrict__ x,
                                           int tile, int r0, int qp) {
    int n = tile * GT + r0;
    if (n >= N_NODES) n = N_NODES - 1;
    const float* xr = x + (size_t)n * D + qp * 16;
    unsigned short* dst = buf + r0 * XPAD + qp * 16;
#pragma unroll
    for (int u = 0; u < 2; ++u) {
        const float4 a = *(const float4*)(xr + u * 8);
        const float4 c = *(const float4*)(xr + u * 8 + 4);
        uint4 v;
        v.x = pk_trunc(a.x, a.y);
        v.y = pk_trunc(a.z, a.w);
        v.z = pk_trunc(c.x, c.y);
        v.w = pk_trunc(c.z, c.w);
        *(uint4*)(dst + u * 8) = v;
    }
}

__device__ __forceinline__ void compute_tile(
    const unsigned short* __restrict__ buf, const bf16x8 (&A)[2][4],
    int tile, int mat, int fh, int quad, int l16,
    unsigned short* __restrict__ yb, unsigned short* __restrict__ resb) {
    f32x4 acc[4][2] = {};
#pragma unroll
    for (int g = 0; g < 4; ++g)
#pragma unroll
        for (int kc = 0; kc < 4; ++kc) {
            const bf16x8 B = *(const bf16x8*)(buf + (g * 16 + l16) * XPAD +
                                              kc * 32 + quad * 8);
            acc[g][0] = __builtin_amdgcn_mfma_f32_16x16x32_bf16(A[0][kc], B, acc[g][0], 0, 0, 0);
            acc[g][1] = __builtin_amdgcn_mfma_f32_16x16x32_bf16(A[1][kc], B, acc[g][1], 0, 0, 0);
        }
    const int nbase = tile * GT;
    unsigned short* dst = mat ? resb : yb;
#pragma unroll
    for (int g = 0; g < 4; ++g) {
        const int n = nbase + g * 16 + l16;
        if (n >= N_NODES) continue;
#pragma unroll
        for (int ft = 0; ft < 2; ++ft) {
            const int f0 = fh + ft * 16 + quad * 4;
            uint2 v;
            v.x = pk_trunc(acc[g][ft][0], acc[g][ft][1]);
            v.y = pk_trunc(acc[g][ft][2], acc[g][ft][3]);
            *(uint2*)(dst + (size_t)n * D + f0) = v;
        }
    }
}

__global__ __launch_bounds__(512) void mfma_gemm(
    const float* __restrict__ x, const unsigned short* __restrict__ wtc,
    const unsigned short* __restrict__ wtr,
    unsigned short* __restrict__ yb, unsigned short* __restrict__ resb) {
    __shared__ unsigned short xs[2][GT * XPAD];

    const int w    = threadIdx.x >> 6;
    const int lane = threadIdx.x & 63;
    const int quad = lane >> 4;
    const int l16  = lane & 15;
    const int mat  = w & 1;
    const int fh   = (w >> 1) * 32;

    const unsigned short* wsrc = mat ? wtr : wtc;
    bf16x8 A[2][4];
#pragma unroll
    for (int ft = 0; ft < 2; ++ft)
#pragma unroll
        for (int kc = 0; kc < 4; ++kc)
            A[ft][kc] = *(const bf16x8*)(wsrc + (fh + ft * 16 + l16) * D +
                                         kc * 32 + quad * 8);

    const int r0 = threadIdx.x >> 3;
    const int qp = threadIdx.x & 7;
    const int t0 = blockIdx.x * 2;

    stage_tile(xs[0], x, t0, r0, qp);
    __syncthreads();
    stage_tile(xs[1], x, t0 + 1, r0, qp);
    compute_tile(xs[0], A, t0, mat, fh, quad, l16, yb, resb);
    __syncthreads();
    compute_tile(xs[1], A, t0 + 1, mat, fh, quad, l16, yb, resb);
}

// ---------------------------------------------------------------------------
// edge aggregation (fused local sort): block = 32-edge bucket (4 segments).
// Counting-sort bucket entries by local edge id in LDS, then the proven
// 16-lane-per-edge gather loop.
// ---------------------------------------------------------------------------
__global__ __launch_bounds__(256) void edge_aggregate(
    const int* __restrict__ bucket_e, const int* __restrict__ gcur_e,
    const unsigned short* __restrict__ yb, unsigned short* __restrict__ efb) {
    __shared__ int raw[SEG_E * ECAP_SEG];
    __shared__ int srt[SEG_E * ECAP_SEG];
    __shared__ int cnt[EBW + 1];
    __shared__ int cur[EBW];
    const int tid = threadIdx.x;
    const int b = blockIdx.x;
    int w[SEG_E], o[SEG_E];
    int W = 0;
#pragma unroll
    for (int s = 0; s < SEG_E; ++s) {
        int c = gcur_e[(b * SEG_E + s) * PADI];
        if (c > ECAP_SEG) c = ECAP_SEG;
        w[s] = c;
        o[s] = W;
        W += c;
    }
    if (tid < EBW + 1) cnt[tid] = 0;
    __syncthreads();
#pragma unroll
    for (int s = 0; s < SEG_E; ++s) {
        const int* src = bucket_e + (b * SEG_E + s) * ECAP_SEG;
        for (int i = tid; i < w[s]; i += 256) {
            const int p = src[i];
            raw[o[s] + i] = p;
            atomicAdd(&cnt[p >> 17], 1);
        }
    }
    __syncthreads();
    if (tid < EBW) {        // wave-0 exclusive scan over 32 bins
        const int c = cnt[tid];
        int v = c;
#pragma unroll
        for (int off = 1; off < EBW; off <<= 1) {
            const int t = __shfl_up(v, off);
            if (tid >= off) v += t;
        }
        cnt[tid] = v - c;
        cur[tid] = v - c;
        if (tid == EBW - 1) cnt[EBW] = v;
    }
    __syncthreads();
    for (int i = tid; i < W; i += 256) {
        const int p = raw[i];
        const int pos = atomicAdd(&cur[p >> 17], 1);
        srt[pos] = p & 0x1FFFF;
    }
    __syncthreads();

    const int g = tid >> 4;       // 16 groups, 2 edges each
    const int l = tid & 15;       // lane = 8 cols (16B)
#pragma unroll
    for (int u = 0; u < 2; ++u) {
        const int el = g * 2 + u;
        const int beg = cnt[el], end = cnt[el + 1];
        float acc[8] = {};
        int j = beg;
        for (; j + 4 <= end; j += 4) {
            const int n0 = srt[j], n1 = srt[j + 1];
            const int n2 = srt[j + 2], n3 = srt[j + 3];
            const bf16x8 p0 = *(const bf16x8*)(yb + (size_t)n0 * D + l * 8);
            const bf16x8 p1 = *(const bf16x8*)(yb + (size_t)n1 * D + l * 8);
            const bf16x8 p2 = *(const bf16x8*)(yb + (size_t)n2 * D + l * 8);
            const bf16x8 p3 = *(const bf16x8*)(yb + (size_t)n3 * D + l * 8);
#pragma unroll
            for (int i = 0; i < 8; ++i)
                acc[i] += (bf2f((unsigned short)p0[i]) + bf2f((unsigned short)p1[i]))
                        + (bf2f((unsigned short)p2[i]) + bf2f((unsigned short)p3[i]));
        }
        for (; j < end; ++j) {
            const bf16x8 p = *(const bf16x8*)(yb + (size_t)srt[j] * D + l * 8);
#pragma unroll
            for (int i = 0; i < 8; ++i) acc[i] += bf2f((unsigned short)p[i]);
        }
        const int deg = end - beg;
        const float inv = deg ? 1.f / (float)deg : 0.f;
        bf16x8 o2;
#pragma unroll
        for (int i = 0; i < 8; ++i) o2[i] = (short)f2bf(acc[i] * inv);
        *(bf16x8*)(efb + (size_t)(b * EBW + el) * D + l * 8) = o2;
    }
}

// ---------------------------------------------------------------------------
// node aggregation (fused local sort): block = 32-node bucket. Sort by local
// node id, gather efb rows, epilogue out = resb + acc*inv + rb + cb.
// Sole writer of out (fp32).
// ---------------------------------------------------------------------------
__global__ __launch_bounds__(256) void node_aggregate(
    const int* __restrict__ bucket_n, const int* __restrict__ gcur_n,
    const unsigned short* __restrict__ efb, const unsigned short* __restrict__ resb,
    const float* __restrict__ rb, const float* __restrict__ cb,
    float* __restrict__ out) {
    __shared__ int raw[NCAP];
    __shared__ int srt[NCAP];
    __shared__ int cnt[NBW + 1];
    __shared__ int cur[NBW];
    const int tid = threadIdx.x;
    const int b = blockIdx.x;
    int W = gcur_n[b * PADI];
    if (W > NCAP) W = NCAP;
    if (tid < NBW + 1) cnt[tid] = 0;
    __syncthreads();
    const int* src = bucket_n + b * NCAP;
    for (int i = tid; i < W; i += 256) {
        const int p = src[i];
        raw[i] = p;
        atomicAdd(&cnt[p >> 15], 1);
    }
    __syncthreads();
    if (tid < NBW) {
        const int c = cnt[tid];
        int v = c;
#pragma unroll
        for (int off = 1; off < NBW; off <<= 1) {
            const int t = __shfl_up(v, off);
            if (tid >= off) v += t;
        }
        cnt[tid] = v - c;
        cur[tid] = v - c;
        if (tid == NBW - 1) cnt[NBW] = v;
    }
    __syncthreads();
    for (int i = tid; i < W; i += 256) {
        const int p = raw[i];
        const int pos = atomicAdd(&cur[p >> 15], 1);
        srt[pos] = p & 0x7FFF;
    }
    __syncthreads();

    const int g = tid >> 4;       // 16 groups, 2 nodes each
    const int l = tid & 15;
#pragma unroll
    for (int u = 0; u < 2; ++u) {
        const int nl = g * 2 + u;
        const int n = b * NBW + nl;
        const int beg = cnt[nl], end = cnt[nl + 1];
        float acc[8] = {};
        int j = beg;
        for (; j + 2 <= end; j += 2) {
            const int e0 = srt[j], e1 = srt[j + 1];
            const bf16x8 p0 = *(const bf16x8*)(efb + (size_t)e0 * D + l * 8);
            const bf16x8 p1 = *(const bf16x8*)(efb + (size_t)e1 * D + l * 8);
#pragma unroll
            for (int i = 0; i < 8; ++i)
                acc[i] += bf2f((unsigned short)p0[i]) + bf2f((unsigned short)p1[i]);
        }
        if (j < end) {
            const bf16x8 p = *(const bf16x8*)(efb + (size_t)srt[j] * D + l * 8);
#pragma unroll
            for (int i = 0; i < 8; ++i) acc[i] += bf2f((unsigned short)p[i]);
        }
        const int deg = end - beg;
        const float inv = deg ? 1.f / (float)deg : 0.f;
        const bf16x8 r = *(const bf16x8*)(resb + (size_t)n * D + l * 8);
        const float4 rb0 = *(const float4*)(rb + l * 8);
        const float4 rb1 = *(const float4*)(rb + l * 8 + 4);
        const float4 cb0 = *(const float4*)(cb + l * 8);
        const float4 cb1 = *(const float4*)(cb + l * 8 + 4);
        float4 o0, o1;
        o0.x = bf2f((unsigned short)r[0]) + acc[0] * inv + rb0.x + cb0.x;
        o0.y = bf2f((unsigned short)r[1]) + acc[1] * inv + rb0.y + cb0.y;
        o0.z = bf2f((unsigned short)r[2]) + acc[2] * inv + rb0.z + cb0.z;
        o0.w = bf2f((unsigned short)r[3]) + acc[3] * inv + rb0.w + cb0.w;
        o1.x = bf2f((unsigned short)r[4]) + acc[4] * inv + rb1.x + cb1.x;
        o1.y = bf2f((unsigned short)r[5]) + acc[5] * inv + rb1.y + cb1.y;
        o1.z = bf2f((unsigned short)r[6]) + acc[6] * inv + rb1.z + cb1.z;
        o1.w = bf2f((unsigned short)r[7]) + acc[7] * inv + rb1.w + cb1.w;
        const size_t o = (size_t)n * D + l * 8;
        *(float4*)(out + o) = o0;
        *(float4*)(out + o + 4) = o1;
    }
}

// ---------------------------------------------------------------------------
extern "C" void kernel_launch(void* const* d_in, const int* in_sizes, int n_in,
                              void* d_out, int out_size, void* d_ws,
                              size_t ws_size, hipStream_t stream) {
    const float* x  = (const float*)d_in[0];
    const int* nidx = (const int*)d_in[1];
    const int* eidx = (const int*)d_in[2];
    const float* cW = (const float*)d_in[3];
    const float* cb = (const float*)d_in[4];
    const float* rW = (const float*)d_in[5];
    const float* rb = (const float*)d_in[6];
    float* out = (float*)d_out;

    char* ws = (char*)d_ws;
    size_t off = 0;
    auto alloc = [&](size_t bytes) {
        size_t o = off;
        off += (bytes + 255) & ~(size_t)255;
        return o;
    };
    unsigned short* yb   = (unsigned short*)(ws + alloc((size_t)N_NODES * D * 2));
    unsigned short* resb = (unsigned short*)(ws + alloc((size_t)N_NODES * D * 2));
    unsigned short* efb  = (unsigned short*)(ws + alloc((size_t)N_EDGES * D * 2));
    unsigned short* wtc  = (unsigned short*)(ws + alloc((size_t)D * D * 2));
    unsigned short* wtr  = (unsigned short*)(ws + alloc((size_t)D * D * 2));
    int* bucket_e = (int*)(ws + alloc((size_t)NBE * SEG_E * ECAP_SEG * 4));
    int* bucket_n = (int*)(ws + alloc((size_t)NBN * NCAP * 4));
    int* gcur     = (int*)(ws + alloc((size_t)GCUR_INTS * 4));
    int* gcur_e = gcur;
    int* gcur_n = gcur + NBE * SEG_E * PADI;

    hipMemsetAsync(gcur, 0, (size_t)GCUR_INTS * 4, stream);

    // bin_pass also produces wtc/wtr (gemm depends on them)
    bin_pass<<<NBLK_A + 8, 256, 0, stream>>>(nidx, eidx, cW, rW, wtc, wtr,
                                             bucket_e, bucket_n, gcur_e, gcur_n);

    mfma_gemm<<<(NTILES + 1) / 2, 512, 0, stream>>>(x, wtc, wtr, yb, resb);

    edge_aggregate<<<NBE, 256, 0, stream>>>(bucket_e, gcur_e, yb, efb);
    node_aggregate<<<NBN, 256, 0, stream>>>(bucket_n, gcur_n, efb, resb,
                                            rb, cb, out);
}

// Round 4
// 203.382 us; speedup vs baseline: 1.7075x; 1.1998x over previous
//
#include <hip/hip_runtime.h>

#define N_NODES 100000
#define N_EDGES 20000
#define NNZ_C   600000
#define D 128

typedef short bf16x8 __attribute__((ext_vector_type(8)));
typedef float f32x4  __attribute__((ext_vector_type(4)));

__device__ __forceinline__ unsigned short f2bf(float f) {
    unsigned int u = __float_as_uint(f);
    u = (u + 0x7fffu + ((u >> 16) & 1u)) >> 16;   // RNE
    return (unsigned short)u;
}
__device__ __forceinline__ float bf2f(unsigned short h) {
    return __uint_as_float((unsigned int)h << 16);
}
// pack two fp32 -> two bf16 (truncation) in one v_perm_b32
__device__ __forceinline__ unsigned int pk_trunc(float lo, float hi) {
    return __builtin_amdgcn_perm(__float_as_uint(hi), __float_as_uint(lo),
                                 0x07060302);
}

// ---------------------------------------------------------------------------
// Two-level binning. Level 1 (bin_coarse): chunk -> LDS sort by coarse mega
// bucket -> contiguous run writes (write-combined, one XCD per line).
// Level 2 (repartition): one block per mega -> LDS sort by exact local id ->
// sorted global CSR (enodes/eptr, nedges/nptr).
// ---------------------------------------------------------------------------
#define CH 2048
#define NBLK_A 293            // ceil(600000/2048)
#define EMW 128               // edges per mega
#define NME 157               // ceil(20000/128)
#define EMCAP 4352            // mean 3822, sigma 62 -> +8.5σ
#define NMW 512               // nodes per mega
#define NMN 196               // ceil(100000/512)
#define NMCAP 3584            // mean 3061, sigma 55 -> +9.5σ
#define PADI 32               // ints per counter line (128 B)
#define GCUR_INTS ((NME + NMN) * PADI)

// ---------------------------------------------------------------------------
// Pass A1: coarse binning, write-combined. Trailing blocks: W transposes.
// ---------------------------------------------------------------------------
__global__ __launch_bounds__(256) void bin_coarse(
    const int* __restrict__ nidx, const int* __restrict__ eidx,
    const float* __restrict__ cW, const float* __restrict__ rW,
    unsigned short* __restrict__ wtc, unsigned short* __restrict__ wtr,
    int* __restrict__ bucket_e, int* __restrict__ bucket_n,
    int* __restrict__ gcur_e, int* __restrict__ gcur_n) {
    __shared__ int rawE[CH], rawN[CH];
    __shared__ int srt[CH];
    __shared__ unsigned char sbin[CH];
    __shared__ int red[256];
    __shared__ int cnt[NMN], lbase[NMN], gbase[NMN], cur[NMN];
    const int bid = blockIdx.x;
    const int tid = threadIdx.x;
    if (bid >= NBLK_A) {   // W transpose: 8 blocks x 4096 elements
        const int t0 = (bid - NBLK_A) * 4096;
        for (int i = tid; i < 4096; i += 256) {
            const int t = t0 + i;
            const int m = t >> 14, idx = t & 16383;
            const int f = idx & 127, k = idx >> 7;
            const float* src = m ? rW : cW;
            unsigned short* dst = m ? wtr : wtc;
            dst[f * D + k] = f2bf(src[k * D + f]);
        }
        return;
    }
    const int j0 = bid * CH;
    const int jn = (j0 + CH < NNZ_C) ? CH : NNZ_C - j0;
    for (int i = tid; i < jn; i += 256) {
        rawE[i] = eidx[j0 + i];
        rawN[i] = nidx[j0 + i];
    }
    __syncthreads();

#pragma unroll
    for (int s = 0; s < 2; ++s) {
        const int nb = s ? NMN : NME;
        int* gc = s ? gcur_n : gcur_e;
        int* dst = s ? bucket_n : bucket_e;
        const int cap = s ? NMCAP : EMCAP;
        for (int i = tid; i < nb; i += 256) cnt[i] = 0;
        __syncthreads();
        for (int i = tid; i < jn; i += 256) {
            const int b = s ? (rawN[i] >> 9) : (rawE[i] >> 7);
            atomicAdd(&cnt[b], 1);
        }
        __syncthreads();
        // exclusive scan over nb (<256 bins) + per-bin global base claim
        const int v = (tid < nb) ? cnt[tid] : 0;
        red[tid] = v;
        __syncthreads();
        for (int off = 1; off < 256; off <<= 1) {
            const int t = (tid >= off) ? red[tid - off] : 0;
            __syncthreads();
            red[tid] += t;
            __syncthreads();
        }
        const int excl = red[tid] - v;
        if (tid < nb) {
            lbase[tid] = excl;
            cur[tid] = excl;
            gbase[tid] = v ? atomicAdd(&gc[tid * PADI], v) : 0;
        }
        __syncthreads();
        // LDS scatter into bin-sorted order
        for (int i = tid; i < jn; i += 256) {
            const int e = rawE[i], n = rawN[i];
            const int b = s ? (n >> 9) : (e >> 7);
            const int pk = s ? (((n & 511) << 15) | e) : (((e & 127) << 17) | n);
            const int pos = atomicAdd(&cur[b], 1);
            srt[pos] = pk;
            sbin[pos] = (unsigned char)b;
        }
        __syncthreads();
        // ordered write-out: runs contiguous per mega
        for (int i = tid; i < jn; i += 256) {
            const int b = sbin[i];
            const int off2 = gbase[b] + (i - lbase[b]);
            if (off2 < cap) dst[b * cap + off2] = srt[i];
        }
        __syncthreads();
    }
}

// ---------------------------------------------------------------------------
// Pass A2: one block per mega bucket -> exact-local-id counting sort -> CSR.
// ---------------------------------------------------------------------------
__global__ __launch_bounds__(256) void repartition(
    const int* __restrict__ bucket_e, const int* __restrict__ bucket_n,
    const int* __restrict__ gcur_e, const int* __restrict__ gcur_n,
    int* __restrict__ eptr, int* __restrict__ nptr,
    int* __restrict__ enodes, int* __restrict__ nedges) {
    __shared__ int raw[EMCAP];
    __shared__ int srt[EMCAP];
    __shared__ int cnt[NMW + 1];
    __shared__ int cur[NMW];
    __shared__ int red[256];
    const int tid = threadIdx.x;
    const int b = blockIdx.x;
    const int side = b >= NME;
    const int cb = side ? b - NME : b;
    const int nbf = side ? NMW : EMW;
    const int L = side ? N_NODES : N_EDGES;
    const int lo = cb * nbf;
    const int nbins = (lo + nbf < L) ? nbf : L - lo;
    const int cap = side ? NMCAP : EMCAP;
    const int shift = side ? 15 : 17;
    const int mask = (1 << shift) - 1;
    const int nmega = side ? NMN : NME;
    const int* gc = side ? gcur_n : gcur_e;
    const int* src = side ? bucket_n + cb * NMCAP : bucket_e + cb * EMCAP;
    int* ptr = side ? nptr : eptr;
    int* dstG = side ? nedges : enodes;

    // global base = sum of clamped counts of megas < cb
    int part = 0;
    for (int i = tid; i < cb; i += 256) {
        int c = gc[i * PADI];
        part += (c < cap) ? c : cap;
    }
    red[tid] = part;
    __syncthreads();
    for (int off = 128; off > 0; off >>= 1) {
        if (tid < off) red[tid] += red[tid + off];
        __syncthreads();
    }
    const int bbase = red[0];
    int W = gc[cb * PADI];
    if (W > cap) W = cap;
    __syncthreads();

    for (int i = tid; i < NMW + 1; i += 256) cnt[i] = 0;
    __syncthreads();
    for (int i = tid; i < W; i += 256) {
        const int p = src[i];
        raw[i] = p;
        atomicAdd(&cnt[p >> shift], 1);
    }
    __syncthreads();
    // exclusive scan over nbf bins (2 slots/thread covers 512)
    const int a0 = cnt[tid * 2], a1 = cnt[tid * 2 + 1];
    const int sum = a0 + a1;
    red[tid] = sum;
    __syncthreads();
    for (int off = 1; off < 256; off <<= 1) {
        const int t = (tid >= off) ? red[tid - off] : 0;
        __syncthreads();
        red[tid] += t;
        __syncthreads();
    }
    const int excl = red[tid] - sum;
    cnt[tid * 2] = excl;
    cnt[tid * 2 + 1] = excl + a0;
    cur[tid * 2] = excl;
    cur[tid * 2 + 1] = excl + a0;
    __syncthreads();
    for (int i = tid; i < nbins; i += 256) ptr[lo + i] = bbase + cnt[i];
    if (cb == nmega - 1 && tid == 0) ptr[L] = bbase + W;
    __syncthreads();
    for (int i = tid; i < W; i += 256) {
        const int p = raw[i];
        const int pos = atomicAdd(&cur[p >> shift], 1);
        srt[pos] = p & mask;
    }
    __syncthreads();
    for (int i = tid; i < W; i += 256) dstG[bbase + i] = srt[i];
}

// ---------------------------------------------------------------------------
// MFMA dual GEMM: weights in registers, x double-buffered in LDS (bf16).
// yb = bf16(x @ cW), resb = bf16(x @ rW)  (bias deferred to node_aggregate)
// ---------------------------------------------------------------------------
#define GT 64
#define XPAD 136
#define NTILES ((N_NODES + GT - 1) / GT)   // 1563

__device__ __forceinline__ void stage_tile(unsigned short* __restrict__ buf,
                                           const float* __restrict__ x,
                                           int tile, int r0, int qp) {
    int n = tile * GT + r0;
    if (n >= N_NODES) n = N_NODES - 1;
    const float* xr = x + (size_t)n * D + qp * 16;
    unsigned short* dst = buf + r0 * XPAD + qp * 16;
#pragma unroll
    for (int u = 0; u < 2; ++u) {
        const float4 a = *(const float4*)(xr + u * 8);
        const float4 c = *(const float4*)(xr + u * 8 + 4);
        uint4 v;
        v.x = pk_trunc(a.x, a.y);
        v.y = pk_trunc(a.z, a.w);
        v.z = pk_trunc(c.x, c.y);
        v.w = pk_trunc(c.z, c.w);
        *(uint4*)(dst + u * 8) = v;
    }
}

__device__ __forceinline__ void compute_tile(
    const unsigned short* __restrict__ buf, const bf16x8 (&A)[2][4],
    int tile, int mat, int fh, int quad, int l16,
    unsigned short* __restrict__ yb, unsigned short* __restrict__ resb) {
    f32x4 acc[4][2] = {};
#pragma unroll
    for (int g = 0; g < 4; ++g)
#pragma unroll
        for (int kc = 0; kc < 4; ++kc) {
            const bf16x8 B = *(const bf16x8*)(buf + (g * 16 + l16) * XPAD +
                                              kc * 32 + quad * 8);
            acc[g][0] = __builtin_amdgcn_mfma_f32_16x16x32_bf16(A[0][kc], B, acc[g][0], 0, 0, 0);
            acc[g][1] = __builtin_amdgcn_mfma_f32_16x16x32_bf16(A[1][kc], B, acc[g][1], 0, 0, 0);
        }
    const int nbase = tile * GT;
    unsigned short* dst = mat ? resb : yb;
#pragma unroll
    for (int g = 0; g < 4; ++g) {
        const int n = nbase + g * 16 + l16;
        if (n >= N_NODES) continue;
#pragma unroll
        for (int ft = 0; ft < 2; ++ft) {
            const int f0 = fh + ft * 16 + quad * 4;
            uint2 v;
            v.x = pk_trunc(acc[g][ft][0], acc[g][ft][1]);
            v.y = pk_trunc(acc[g][ft][2], acc[g][ft][3]);
            *(uint2*)(dst + (size_t)n * D + f0) = v;
        }
    }
}

__global__ __launch_bounds__(512) void mfma_gemm(
    const float* __restrict__ x, const unsigned short* __restrict__ wtc,
    const unsigned short* __restrict__ wtr,
    unsigned short* __restrict__ yb, unsigned short* __restrict__ resb) {
    __shared__ unsigned short xs[2][GT * XPAD];

    const int w    = threadIdx.x >> 6;
    const int lane = threadIdx.x & 63;
    const int quad = lane >> 4;
    const int l16  = lane & 15;
    const int mat  = w & 1;
    const int fh   = (w >> 1) * 32;

    const unsigned short* wsrc = mat ? wtr : wtc;
    bf16x8 A[2][4];
#pragma unroll
    for (int ft = 0; ft < 2; ++ft)
#pragma unroll
        for (int kc = 0; kc < 4; ++kc)
            A[ft][kc] = *(const bf16x8*)(wsrc + (fh + ft * 16 + l16) * D +
                                         kc * 32 + quad * 8);

    const int r0 = threadIdx.x >> 3;
    const int qp = threadIdx.x & 7;
    const int t0 = blockIdx.x * 2;

    stage_tile(xs[0], x, t0, r0, qp);
    __syncthreads();
    stage_tile(xs[1], x, t0 + 1, r0, qp);
    compute_tile(xs[0], A, t0, mat, fh, quad, l16, yb, resb);
    __syncthreads();
    compute_tile(xs[1], A, t0 + 1, mat, fh, quad, l16, yb, resb);
}

// ---------------------------------------------------------------------------
// edge aggregation: 16-lane group per edge, pure CSR gather.
// ---------------------------------------------------------------------------
__global__ __launch_bounds__(256) void edge_aggregate(
    const unsigned short* __restrict__ yb, const int* __restrict__ eptr,
    const int* __restrict__ enodes, unsigned short* __restrict__ efb) {
    const int e = blockIdx.x * 16 + (threadIdx.x >> 4);
    const int l = threadIdx.x & 15;
    const int beg = eptr[e], end = eptr[e + 1];
    float acc[8] = {};
    int j = beg;
    for (; j + 4 <= end; j += 4) {
        const int n0 = enodes[j], n1 = enodes[j + 1];
        const int n2 = enodes[j + 2], n3 = enodes[j + 3];
        const bf16x8 p0 = *(const bf16x8*)(yb + (size_t)n0 * D + l * 8);
        const bf16x8 p1 = *(const bf16x8*)(yb + (size_t)n1 * D + l * 8);
        const bf16x8 p2 = *(const bf16x8*)(yb + (size_t)n2 * D + l * 8);
        const bf16x8 p3 = *(const bf16x8*)(yb + (size_t)n3 * D + l * 8);
#pragma unroll
        for (int i = 0; i < 8; ++i)
            acc[i] += (bf2f((unsigned short)p0[i]) + bf2f((unsigned short)p1[i]))
                    + (bf2f((unsigned short)p2[i]) + bf2f((unsigned short)p3[i]));
    }
    for (; j < end; ++j) {
        const bf16x8 p = *(const bf16x8*)(yb + (size_t)enodes[j] * D + l * 8);
#pragma unroll
        for (int i = 0; i < 8; ++i) acc[i] += bf2f((unsigned short)p[i]);
    }
    const int deg = end - beg;
    const float inv = deg ? 1.f / (float)deg : 0.f;
    bf16x8 o;
#pragma unroll
    for (int i = 0; i < 8; ++i) o[i] = (short)f2bf(acc[i] * inv);
    *(bf16x8*)(efb + (size_t)e * D + l * 8) = o;
}

// ---------------------------------------------------------------------------
// node aggregation: 16-lane group per node; out = resb + acc*inv + rb + cb.
// Sole writer of out (fp32).
// ---------------------------------------------------------------------------
__global__ __launch_bounds__(256) void node_aggregate(
    const unsigned short* __restrict__ efb, const int* __restrict__ nptr,
    const int* __restrict__ nedges, const unsigned short* __restrict__ resb,
    const float* __restrict__ rb, const float* __restrict__ cb,
    float* __restrict__ out) {
    const int n = blockIdx.x * 16 + (threadIdx.x >> 4);
    const int l = threadIdx.x & 15;
    const int beg = nptr[n], end = nptr[n + 1];
    float acc[8] = {};
    int j = beg;
    for (; j + 2 <= end; j += 2) {
        const int e0 = nedges[j], e1 = nedges[j + 1];
        const bf16x8 p0 = *(const bf16x8*)(efb + (size_t)e0 * D + l * 8);
        const bf16x8 p1 = *(const bf16x8*)(efb + (size_t)e1 * D + l * 8);
#pragma unroll
        for (int i = 0; i < 8; ++i)
            acc[i] += bf2f((unsigned short)p0[i]) + bf2f((unsigned short)p1[i]);
    }
    if (j < end) {
        const bf16x8 p = *(const bf16x8*)(efb + (size_t)nedges[j] * D + l * 8);
#pragma unroll
        for (int i = 0; i < 8; ++i) acc[i] += bf2f((unsigned short)p[i]);
    }
    const int deg = end - beg;
    const float inv = deg ? 1.f / (float)deg : 0.f;
    const bf16x8 r = *(const bf16x8*)(resb + (size_t)n * D + l * 8);
    const float4 rb0 = *(const float4*)(rb + l * 8);
    const float4 rb1 = *(const float4*)(rb + l * 8 + 4);
    const float4 cb0 = *(const float4*)(cb + l * 8);
    const float4 cb1 = *(const float4*)(cb + l * 8 + 4);
    float4 o0, o1;
    o0.x = bf2f((unsigned short)r[0]) + acc[0] * inv + rb0.x + cb0.x;
    o0.y = bf2f((unsigned short)r[1]) + acc[1] * inv + rb0.y + cb0.y;
    o0.z = bf2f((unsigned short)r[2]) + acc[2] * inv + rb0.z + cb0.z;
    o0.w = bf2f((unsigned short)r[3]) + acc[3] * inv + rb0.w + cb0.w;
    o1.x = bf2f((unsigned short)r[4]) + acc[4] * inv + rb1.x + cb1.x;
    o1.y = bf2f((unsigned short)r[5]) + acc[5] * inv + rb1.y + cb1.y;
    o1.z = bf2f((unsigned short)r[6]) + acc[6] * inv + rb1.z + cb1.z;
    o1.w = bf2f((unsigned short)r[7]) + acc[7] * inv + rb1.w + cb1.w;
    const size_t o = (size_t)n * D + l * 8;
    *(float4*)(out + o) = o0;
    *(float4*)(out + o + 4) = o1;
}

// ---------------------------------------------------------------------------
extern "C" void kernel_launch(void* const* d_in, const int* in_sizes, int n_in,
                              void* d_out, int out_size, void* d_ws,
                              size_t ws_size, hipStream_t stream) {
    const float* x  = (const float*)d_in[0];
    const int* nidx = (const int*)d_in[1];
    const int* eidx = (const int*)d_in[2];
    const float* cW = (const float*)d_in[3];
    const float* cb = (const float*)d_in[4];
    const float* rW = (const float*)d_in[5];
    const float* rb = (const float*)d_in[6];
    float* out = (float*)d_out;

    char* ws = (char*)d_ws;
    size_t off = 0;
    auto alloc = [&](size_t bytes) {
        size_t o = off;
        off += (bytes + 255) & ~(size_t)255;
        return o;
    };
    unsigned short* yb   = (unsigned short*)(ws + alloc((size_t)N_NODES * D * 2));
    unsigned short* resb = (unsigned short*)(ws + alloc((size_t)N_NODES * D * 2));
    unsigned short* efb  = (unsigned short*)(ws + alloc((size_t)N_EDGES * D * 2));
    unsigned short* wtc  = (unsigned short*)(ws + alloc((size_t)D * D * 2));
    unsigned short* wtr  = (unsigned short*)(ws + alloc((size_t)D * D * 2));
    int* bucket_e = (int*)(ws + alloc((size_t)NME * EMCAP * 4));
    int* bucket_n = (int*)(ws + alloc((size_t)NMN * NMCAP * 4));
    int* enodes   = (int*)(ws + alloc((size_t)NNZ_C * 4));
    int* nedges   = (int*)(ws + alloc((size_t)NNZ_C * 4));
    int* eptr     = (int*)(ws + alloc((size_t)(N_EDGES + 1) * 4));
    int* nptr     = (int*)(ws + alloc((size_t)(N_NODES + 1) * 4));
    int* gcur     = (int*)(ws + alloc((size_t)GCUR_INTS * 4));
    int* gcur_e = gcur;
    int* gcur_n = gcur + NME * PADI;

    hipMemsetAsync(gcur, 0, (size_t)GCUR_INTS * 4, stream);

    // bin_coarse also produces wtc/wtr (gemm depends on them)
    bin_coarse<<<NBLK_A + 8, 256, 0, stream>>>(nidx, eidx, cW, rW, wtc, wtr,
                                               bucket_e, bucket_n, gcur_e, gcur_n);

    mfma_gemm<<<(NTILES + 1) / 2, 512, 0, stream>>>(x, wtc, wtr, yb, resb);

    repartition<<<NME + NMN, 256, 0, stream>>>(bucket_e, bucket_n,
                                               gcur_e, gcur_n,
                                               eptr, nptr, enodes, nedges);

    edge_aggregate<<<N_EDGES / 16, 256, 0, stream>>>(yb, eptr, enodes, efb);
    node_aggregate<<<N_NODES / 16, 256, 0, stream>>>(efb, nptr, nedges, resb,
                                                     rb, cb, out);
}

// Round 5
// 197.930 us; speedup vs baseline: 1.7546x; 1.0275x over previous
//
#include <hip/hip_runtime.h>

#define N_NODES 100000
#define N_EDGES 20000
#define NNZ_C   600000
#define D 128

typedef short bf16x8 __attribute__((ext_vector_type(8)));
typedef float f32x4  __attribute__((ext_vector_type(4)));

__device__ __forceinline__ unsigned short f2bf(float f) {
    unsigned int u = __float_as_uint(f);
    u = (u + 0x7fffu + ((u >> 16) & 1u)) >> 16;   // RNE
    return (unsigned short)u;
}
__device__ __forceinline__ float bf2f(unsigned short h) {
    return __uint_as_float((unsigned int)h << 16);
}
// pack two fp32 -> two bf16 (truncation) in one v_perm_b32
__device__ __forceinline__ unsigned int pk_trunc(float lo, float hi) {
    return __builtin_amdgcn_perm(__float_as_uint(hi), __float_as_uint(lo),
                                 0x07060302);
}

// ---------------------------------------------------------------------------
// Fine buckets, write-combined two-phase claim inside the chunked binner.
// Edge buckets: 32 edges (625, exact). Node buckets: 128 nodes (782).
// Aggregators counting-sort their own bucket in LDS (no repartition pass).
// ---------------------------------------------------------------------------
#define CH 2048
#define NCHUNK 293            // ceil(600000/2048)
#define EBW 32                // edges per bucket
#define NBE 625               // 20000/32 exact
#define ECAP 1280             // mean 960, sigma 31 -> +10.3σ
#define NBW 128               // nodes per bucket
#define NBN 782               // ceil(100000/128)
#define NCAP 1024             // mean 768, sigma 27.7 -> +9.2σ
#define PADI 32               // ints per counter line (128 B)
#define GCUR_INTS ((NBE + NBN) * PADI)

#define GT 64
#define XPAD 136
#define NTILES ((N_NODES + GT - 1) / GT)   // 1563
#define GEMM_BLKS ((NTILES + 1) / 2)       // 782

// ---------------------------------------------------------------------------
// GEMM helpers (unchanged math): yb = bf16(x@cW), resb = bf16(x@rW)
// ---------------------------------------------------------------------------
__device__ __forceinline__ void stage_tile(unsigned short* __restrict__ buf,
                                           const float* __restrict__ x,
                                           int tile, int r0, int qp) {
    int n = tile * GT + r0;
    if (n >= N_NODES) n = N_NODES - 1;
    const float* xr = x + (size_t)n * D + qp * 16;
    unsigned short* dst = buf + r0 * XPAD + qp * 16;
#pragma unroll
    for (int u = 0; u < 2; ++u) {
        const float4 a = *(const float4*)(xr + u * 8);
        const float4 c = *(const float4*)(xr + u * 8 + 4);
        uint4 v;
        v.x = pk_trunc(a.x, a.y);
        v.y = pk_trunc(a.z, a.w);
        v.z = pk_trunc(c.x, c.y);
        v.w = pk_trunc(c.z, c.w);
        *(uint4*)(dst + u * 8) = v;
    }
}

__device__ __forceinline__ void compute_tile(
    const unsigned short* __restrict__ buf, const bf16x8 (&A)[2][4],
    int tile, int mat, int fh, int quad, int l16,
    unsigned short* __restrict__ yb, unsigned short* __restrict__ resb) {
    f32x4 acc[4][2] = {};
#pragma unroll
    for (int g = 0; g < 4; ++g)
#pragma unroll
        for (int kc = 0; kc < 4; ++kc) {
            const bf16x8 B = *(const bf16x8*)(buf + (g * 16 + l16) * XPAD +
                                              kc * 32 + quad * 8);
            acc[g][0] = __builtin_amdgcn_mfma_f32_16x16x32_bf16(A[0][kc], B, acc[g][0], 0, 0, 0);
            acc[g][1] = __builtin_amdgcn_mfma_f32_16x16x32_bf16(A[1][kc], B, acc[g][1], 0, 0, 0);
        }
    const int nbase = tile * GT;
    unsigned short* dst = mat ? resb : yb;
#pragma unroll
    for (int g = 0; g < 4; ++g) {
        const int n = nbase + g * 16 + l16;
        if (n >= N_NODES) continue;
#pragma unroll
        for (int ft = 0; ft < 2; ++ft) {
            const int f0 = fh + ft * 16 + quad * 4;
            uint2 v;
            v.x = pk_trunc(acc[g][ft][0], acc[g][ft][1]);
            v.y = pk_trunc(acc[g][ft][2], acc[g][ft][3]);
            *(uint2*)(dst + (size_t)n * D + f0) = v;
        }
    }
}

// ---------------------------------------------------------------------------
// Fused kernel: blocks [0,293) do chunked write-combined binning; blocks
// [293, 293+782) do the dual GEMM with W read directly from fp32 (no wt
// pre-pass). Independent work overlaps in one launch.
// ---------------------------------------------------------------------------
__global__ __launch_bounds__(512) void fused_bin_gemm(
    const float* __restrict__ x,
    const int* __restrict__ nidx, const int* __restrict__ eidx,
    const float* __restrict__ cW, const float* __restrict__ rW,
    unsigned short* __restrict__ yb, unsigned short* __restrict__ resb,
    int* __restrict__ bucket_e, int* __restrict__ bucket_n,
    int* __restrict__ gcur_e, int* __restrict__ gcur_n) {
    __shared__ int lds[10816];   // 43264 B pool, shared by both roles
    const int bid = blockIdx.x;
    const int tid = threadIdx.x;

    if (bid < NCHUNK) {
        // ---------------- bin role ----------------
        int* rawE  = lds;            // 2048
        int* rawN  = lds + 2048;     // 2048
        int* srt   = lds + 4096;     // 2048
        int* red   = lds + 6144;     // 512
        int* cnt   = lds + 6656;     // 782
        int* lbase = lds + 7438;     // 782
        int* gbase = lds + 8220;     // 782
        int* cur   = lds + 9002;     // 782
        unsigned short* sbin = (unsigned short*)(lds + 9784);  // 2048 ushort
        const int j0 = bid * CH;
        const int jn = (j0 + CH < NNZ_C) ? CH : NNZ_C - j0;
        for (int i = tid; i < jn; i += 512) {
            rawE[i] = eidx[j0 + i];
            rawN[i] = nidx[j0 + i];
        }
        __syncthreads();
#pragma unroll
        for (int s = 0; s < 2; ++s) {
            const int nb = s ? NBN : NBE;
            int* gc = s ? gcur_n : gcur_e;
            int* dst = s ? bucket_n : bucket_e;
            const int cap = s ? NCAP : ECAP;
            for (int i = tid; i < nb; i += 512) cnt[i] = 0;
            __syncthreads();
            for (int i = tid; i < jn; i += 512)
                atomicAdd(&cnt[s ? (rawN[i] >> 7) : (rawE[i] >> 5)], 1);
            __syncthreads();
            // 2-slot exclusive scan + per-bin global base claim
            const int i0 = tid * 2, i1 = tid * 2 + 1;
            const int a0 = (i0 < nb) ? cnt[i0] : 0;
            const int a1 = (i1 < nb) ? cnt[i1] : 0;
            const int sum = a0 + a1;
            red[tid] = sum;
            __syncthreads();
            for (int off = 1; off < 512; off <<= 1) {
                const int t = (tid >= off) ? red[tid - off] : 0;
                __syncthreads();
                red[tid] += t;
                __syncthreads();
            }
            const int excl = red[tid] - sum;
            if (i0 < nb) {
                lbase[i0] = excl; cur[i0] = excl;
                gbase[i0] = a0 ? atomicAdd(&gc[i0 * PADI], a0) : 0;
            }
            if (i1 < nb) {
                lbase[i1] = excl + a0; cur[i1] = excl + a0;
                gbase[i1] = a1 ? atomicAdd(&gc[i1 * PADI], a1) : 0;
            }
            __syncthreads();
            // LDS scatter into bin-sorted order
            for (int i = tid; i < jn; i += 512) {
                const int e = rawE[i], n = rawN[i];
                const int b = s ? (n >> 7) : (e >> 5);
                const int pk = s ? (((n & 127) << 15) | e)
                                 : (((e & 31) << 17) | n);
                const int pos = atomicAdd(&cur[b], 1);
                srt[pos] = pk;
                sbin[pos] = (unsigned short)b;
            }
            __syncthreads();
            // ordered write-out: contiguous run per bucket (write-combined)
            for (int i = tid; i < jn; i += 512) {
                const int b = sbin[i];
                const int o2 = gbase[b] + (i - lbase[b]);
                if (o2 < cap) dst[b * cap + o2] = srt[i];
            }
            __syncthreads();
        }
        return;
    }

    // ---------------- gemm role ----------------
    unsigned short* xs0 = (unsigned short*)lds;
    unsigned short* xs1 = xs0 + GT * XPAD;

    const int w    = tid >> 6;
    const int lane = tid & 63;
    const int quad = lane >> 4;
    const int l16  = lane & 15;
    const int mat  = w & 1;
    const int fh   = (w >> 1) * 32;
    const int r0 = tid >> 3;
    const int qp = tid & 7;
    const int t0 = (bid - NCHUNK) * 2;

    stage_tile(xs0, x, t0, r0, qp);

    // W fragments read directly from fp32 (L2-resident, coalesced in l16)
    const float* wf = mat ? rW : cW;
    bf16x8 A[2][4];
#pragma unroll
    for (int ft = 0; ft < 2; ++ft) {
        const int f = fh + ft * 16 + l16;
#pragma unroll
        for (int kc = 0; kc < 4; ++kc)
#pragma unroll
            for (int u = 0; u < 8; ++u)
                A[ft][kc][u] = (short)f2bf(wf[(kc * 32 + quad * 8 + u) * D + f]);
    }
    __syncthreads();
    stage_tile(xs1, x, t0 + 1, r0, qp);
    compute_tile(xs0, A, t0, mat, fh, quad, l16, yb, resb);
    __syncthreads();
    compute_tile(xs1, A, t0 + 1, mat, fh, quad, l16, yb, resb);
}

// ---------------------------------------------------------------------------
// edge aggregation (fused local sort): block = 32-edge bucket, 512 threads.
// Counting-sort in LDS, then 32 x 16-lane groups, one edge each.
// ---------------------------------------------------------------------------
__global__ __launch_bounds__(512) void edge_aggregate(
    const int* __restrict__ bucket_e, const int* __restrict__ gcur_e,
    const unsigned short* __restrict__ yb, unsigned short* __restrict__ efb) {
    __shared__ int raw[ECAP];
    __shared__ int srt[ECAP];
    __shared__ int cnt[EBW + 1];
    __shared__ int cur[EBW];
    const int tid = threadIdx.x;
    const int b = blockIdx.x;
    int W = gcur_e[b * PADI];
    if (W > ECAP) W = ECAP;
    if (tid <= EBW) cnt[tid] = 0;
    __syncthreads();
    const int* src = bucket_e + b * ECAP;
    for (int i = tid; i < W; i += 512) {
        const int p = src[i];
        raw[i] = p;
        atomicAdd(&cnt[p >> 17], 1);
    }
    __syncthreads();
    if (tid < EBW) {        // wave-0 exclusive scan over 32 bins
        const int c = cnt[tid];
        int v = c;
#pragma unroll
        for (int off = 1; off < EBW; off <<= 1) {
            const int t = __shfl_up(v, off);
            if (tid >= off) v += t;
        }
        cnt[tid] = v - c;
        cur[tid] = v - c;
        if (tid == EBW - 1) cnt[EBW] = v;
    }
    __syncthreads();
    for (int i = tid; i < W; i += 512) {
        const int p = raw[i];
        const int pos = atomicAdd(&cur[p >> 17], 1);
        srt[pos] = p & 0x1FFFF;
    }
    __syncthreads();

    const int g = tid >> 4;       // 32 groups, 1 edge each
    const int l = tid & 15;       // lane = 8 cols (16B)
    const int beg = cnt[g], end = cnt[g + 1];
    float acc[8] = {};
    int j = beg;
    for (; j + 4 <= end; j += 4) {
        const int n0 = srt[j], n1 = srt[j + 1];
        const int n2 = srt[j + 2], n3 = srt[j + 3];
        const bf16x8 p0 = *(const bf16x8*)(yb + (size_t)n0 * D + l * 8);
        const bf16x8 p1 = *(const bf16x8*)(yb + (size_t)n1 * D + l * 8);
        const bf16x8 p2 = *(const bf16x8*)(yb + (size_t)n2 * D + l * 8);
        const bf16x8 p3 = *(const bf16x8*)(yb + (size_t)n3 * D + l * 8);
#pragma unroll
        for (int i = 0; i < 8; ++i)
            acc[i] += (bf2f((unsigned short)p0[i]) + bf2f((unsigned short)p1[i]))
                    + (bf2f((unsigned short)p2[i]) + bf2f((unsigned short)p3[i]));
    }
    for (; j < end; ++j) {
        const bf16x8 p = *(const bf16x8*)(yb + (size_t)srt[j] * D + l * 8);
#pragma unroll
        for (int i = 0; i < 8; ++i) acc[i] += bf2f((unsigned short)p[i]);
    }
    const int deg = end - beg;
    const float inv = deg ? 1.f / (float)deg : 0.f;
    bf16x8 o;
#pragma unroll
    for (int i = 0; i < 8; ++i) o[i] = (short)f2bf(acc[i] * inv);
    *(bf16x8*)(efb + (size_t)(b * EBW + g) * D + l * 8) = o;   // 625*32 = 20000 exact
}

// ---------------------------------------------------------------------------
// node aggregation (fused local sort): block = 128-node bucket, 512 threads.
// Sort by local node id, 32 groups x 4 nodes; out = resb + acc*inv + rb + cb.
// ---------------------------------------------------------------------------
__global__ __launch_bounds__(512) void node_aggregate(
    const int* __restrict__ bucket_n, const int* __restrict__ gcur_n,
    const unsigned short* __restrict__ efb, const unsigned short* __restrict__ resb,
    const float* __restrict__ rb, const float* __restrict__ cb,
    float* __restrict__ out) {
    __shared__ int raw[NCAP];
    __shared__ int srt[NCAP];
    __shared__ int cnt[NBW + 1];
    __shared__ int cur[NBW];
    __shared__ int red[512];
    const int tid = threadIdx.x;
    const int b = blockIdx.x;
    int W = gcur_n[b * PADI];
    if (W > NCAP) W = NCAP;
    if (tid <= NBW) cnt[tid] = 0;
    __syncthreads();
    const int* src = bucket_n + b * NCAP;
    for (int i = tid; i < W; i += 512) {
        const int p = src[i];
        raw[i] = p;
        atomicAdd(&cnt[p >> 15], 1);
    }
    __syncthreads();
    const int v = (tid < NBW) ? cnt[tid] : 0;
    red[tid] = v;
    __syncthreads();
    for (int off = 1; off < 512; off <<= 1) {
        const int t = (tid >= off) ? red[tid - off] : 0;
        __syncthreads();
        red[tid] += t;
        __syncthreads();
    }
    const int excl = red[tid] - v;
    if (tid < NBW) { cnt[tid] = excl; cur[tid] = excl; }
    if (tid == NBW - 1) cnt[NBW] = red[tid];
    __syncthreads();
    for (int i = tid; i < W; i += 512) {
        const int p = raw[i];
        const int pos = atomicAdd(&cur[p >> 15], 1);
        srt[pos] = p & 0x7FFF;
    }
    __syncthreads();

    const int g = tid >> 4;       // 32 groups, 4 nodes each
    const int l = tid & 15;
    const float4 rb0 = *(const float4*)(rb + l * 8);
    const float4 rb1 = *(const float4*)(rb + l * 8 + 4);
    const float4 cb0 = *(const float4*)(cb + l * 8);
    const float4 cb1 = *(const float4*)(cb + l * 8 + 4);
#pragma unroll
    for (int u = 0; u < 4; ++u) {
        const int nl = g * 4 + u;
        const int n = b * NBW + nl;
        if (n >= N_NODES) continue;
        const int beg = cnt[nl], end = cnt[nl + 1];
        float acc[8] = {};
        int j = beg;
        for (; j + 2 <= end; j += 2) {
            const int e0 = srt[j], e1 = srt[j + 1];
            const bf16x8 p0 = *(const bf16x8*)(efb + (size_t)e0 * D + l * 8);
            const bf16x8 p1 = *(const bf16x8*)(efb + (size_t)e1 * D + l * 8);
#pragma unroll
            for (int i = 0; i < 8; ++i)
                acc[i] += bf2f((unsigned short)p0[i]) + bf2f((unsigned short)p1[i]);
        }
        if (j < end) {
            const bf16x8 p = *(const bf16x8*)(efb + (size_t)srt[j] * D + l * 8);
#pragma unroll
            for (int i = 0; i < 8; ++i) acc[i] += bf2f((unsigned short)p[i]);
        }
        const int deg = end - beg;
        const float inv = deg ? 1.f / (float)deg : 0.f;
        const bf16x8 r = *(const bf16x8*)(resb + (size_t)n * D + l * 8);
        float4 o0, o1;
        o0.x = bf2f((unsigned short)r[0]) + acc[0] * inv + rb0.x + cb0.x;
        o0.y = bf2f((unsigned short)r[1]) + acc[1] * inv + rb0.y + cb0.y;
        o0.z = bf2f((unsigned short)r[2]) + acc[2] * inv + rb0.z + cb0.z;
        o0.w = bf2f((unsigned short)r[3]) + acc[3] * inv + rb0.w + cb0.w;
        o1.x = bf2f((unsigned short)r[4]) + acc[4] * inv + rb1.x + cb1.x;
        o1.y = bf2f((unsigned short)r[5]) + acc[5] * inv + rb1.y + cb1.y;
        o1.z = bf2f((unsigned short)r[6]) + acc[6] * inv + rb1.z + cb1.z;
        o1.w = bf2f((unsigned short)r[7]) + acc[7] * inv + rb1.w + cb1.w;
        const size_t o = (size_t)n * D + l * 8;
        *(float4*)(out + o) = o0;
        *(float4*)(out + o + 4) = o1;
    }
}

// ---------------------------------------------------------------------------
extern "C" void kernel_launch(void* const* d_in, const int* in_sizes, int n_in,
                              void* d_out, int out_size, void* d_ws,
                              size_t ws_size, hipStream_t stream) {
    const float* x  = (const float*)d_in[0];
    const int* nidx = (const int*)d_in[1];
    const int* eidx = (const int*)d_in[2];
    const float* cW = (const float*)d_in[3];
    const float* cb = (const float*)d_in[4];
    const float* rW = (const float*)d_in[5];
    const float* rb = (const float*)d_in[6];
    float* out = (float*)d_out;

    char* ws = (char*)d_ws;
    size_t off = 0;
    auto alloc = [&](size_t bytes) {
        size_t o = off;
        off += (bytes + 255) & ~(size_t)255;
        return o;
    };
    unsigned short* yb   = (unsigned short*)(ws + alloc((size_t)N_NODES * D * 2));
    unsigned short* resb = (unsigned short*)(ws + alloc((size_t)N_NODES * D * 2));
    unsigned short* efb  = (unsigned short*)(ws + alloc((size_t)N_EDGES * D * 2));
    int* bucket_e = (int*)(ws + alloc((size_t)NBE * ECAP * 4));
    int* bucket_n = (int*)(ws + alloc((size_t)NBN * NCAP * 4));
    int* gcur     = (int*)(ws + alloc((size_t)GCUR_INTS * 4));
    int* gcur_e = gcur;
    int* gcur_n = gcur + NBE * PADI;

    hipMemsetAsync(gcur, 0, (size_t)GCUR_INTS * 4, stream);

    fused_bin_gemm<<<NCHUNK + GEMM_BLKS, 512, 0, stream>>>(
        x, nidx, eidx, cW, rW, yb, resb,
        bucket_e, bucket_n, gcur_e, gcur_n);

    edge_aggregate<<<NBE, 512, 0, stream>>>(bucket_e, gcur_e, yb, efb);
    node_aggregate<<<NBN, 512, 0, stream>>>(bucket_n, gcur_n, efb, resb,
                                            rb, cb, out);
}

// Round 6
// 193.270 us; speedup vs baseline: 1.7969x; 1.0241x over previous
//
#include <hip/hip_runtime.h>

#define N_NODES 100000
#define N_EDGES 20000
#define NNZ_C   600000
#define D 128

typedef short bf16x8 __attribute__((ext_vector_type(8)));
typedef float f32x4  __attribute__((ext_vector_type(4)));

__device__ __forceinline__ unsigned short f2bf(float f) {
    unsigned int u = __float_as_uint(f);
    u = (u + 0x7fffu + ((u >> 16) & 1u)) >> 16;   // RNE
    return (unsigned short)u;
}
__device__ __forceinline__ float bf2f(unsigned short h) {
    return __uint_as_float((unsigned int)h << 16);
}
// pack two fp32 -> two bf16 (truncation) in one v_perm_b32
__device__ __forceinline__ unsigned int pk_trunc(float lo, float hi) {
    return __builtin_amdgcn_perm(__float_as_uint(hi), __float_as_uint(lo),
                                 0x07060302);
}

// ---------------------------------------------------------------------------
// Math plan (linearity): out = (D^-1 H B^-1 H^T xb) @ cW + xb @ rW + (cb+rb)
//   1. fused_bin_conv : bucket COO (write-combined) + xb = bf16(x)
//   2. edge_mean      : s_e = mean_{n in e} xb[n]        (sort-in-LDS gather)
//   3. node_mean      : z_n = mean_{e at n} s[e]
//   4. final_gemm     : out = z@cW + xb@rW + biases      (sole out writer)
// ---------------------------------------------------------------------------
#define CH 4096
#define NCHUNK 147            // ceil(600000/4096)
#define CONVB 256             // x->bf16 convert blocks (grid-stride)
#define EBW 32                // edges per bucket
#define NBE 625               // 20000/32 exact
#define ECAP 1280             // mean 960, sigma 31 -> +10.3σ
#define NBW 128               // nodes per bucket
#define NBN 782               // ceil(100000/128)
#define NCAP 1024             // mean 768, sigma 27.7 -> +9.2σ
#define PADI 32               // ints per counter line (128 B)
#define GCUR_INTS ((NBE + NBN) * PADI)

#define GT 64
#define XPAD 136
#define NTILES ((N_NODES + GT - 1) / GT)   // 1563
#define TPB 3                              // tiles per final_gemm block
#define GEMM_BLKS ((NTILES + TPB - 1) / TPB)  // 521

// ---------------------------------------------------------------------------
// Kernel 1: blocks [0,147) bin the COO; blocks [147,403) convert x -> bf16.
// Bin role: histogram (global re-read) -> wave0 scan -> parallel base claim
// on line-padded counters -> LDS bin-sort -> contiguous run write-out.
// Bucket id rides in bits 22..31 of the packed value (stripped on write).
// ---------------------------------------------------------------------------
__global__ __launch_bounds__(512) void fused_bin_conv(
    const float* __restrict__ x,
    const int* __restrict__ nidx, const int* __restrict__ eidx,
    unsigned short* __restrict__ xb,
    int* __restrict__ bucket_e, int* __restrict__ bucket_n,
    int* __restrict__ gcur_e, int* __restrict__ gcur_n) {
    __shared__ int srt[CH];
    __shared__ int cnt[NBN], lbase[NBN], gbase[NBN], cur[NBN];
    const int bid = blockIdx.x;
    const int tid = threadIdx.x;

    if (bid >= NCHUNK) {
        // -------- convert role: xb = bf16(x), grid-stride over 8-elt groups
        const int total8 = N_NODES * D / 8;           // 1.6M
        for (int g = (bid - NCHUNK) * 512 + tid; g < total8;
             g += CONVB * 512) {
            const float4 a = *(const float4*)(x + (size_t)g * 8);
            const float4 c = *(const float4*)(x + (size_t)g * 8 + 4);
            uint4 v;
            v.x = pk_trunc(a.x, a.y);
            v.y = pk_trunc(a.z, a.w);
            v.z = pk_trunc(c.x, c.y);
            v.w = pk_trunc(c.z, c.w);
            *(uint4*)(xb + (size_t)g * 8) = v;
        }
        return;
    }

    // -------- bin role
    const int j0 = bid * CH;
    const int jn = (j0 + CH < NNZ_C) ? CH : NNZ_C - j0;
#pragma unroll
    for (int s = 0; s < 2; ++s) {
        const int nb = s ? NBN : NBE;
        int* gc = s ? gcur_n : gcur_e;
        int* dst = s ? bucket_n : bucket_e;
        const int cap = s ? NCAP : ECAP;
        for (int i = tid; i < nb; i += 512) cnt[i] = 0;
        __syncthreads();
        for (int i = tid; i < jn; i += 512) {
            const int id = s ? nidx[j0 + i] : eidx[j0 + i];
            atomicAdd(&cnt[s ? (id >> 7) : (id >> 5)], 1);
        }
        __syncthreads();
        // wave-0 scan: 13 bins/lane covers 782
        if (tid < 64) {
            int loc[13];
            int ssum = 0;
            const int k0 = tid * 13;
#pragma unroll
            for (int k = 0; k < 13; ++k) {
                const int idx = k0 + k;
                loc[k] = ssum;
                if (idx < nb) ssum += cnt[idx];
            }
            int v = ssum;
#pragma unroll
            for (int off = 1; off < 64; off <<= 1) {
                const int t = __shfl_up(v, off);
                if (tid >= off) v += t;
            }
            const int base = v - ssum;
#pragma unroll
            for (int k = 0; k < 13; ++k) {
                const int idx = k0 + k;
                if (idx < nb) {
                    lbase[idx] = base + loc[k];
                    cur[idx] = base + loc[k];
                }
            }
        }
        __syncthreads();
        // parallel per-bucket global base claim (padded counters)
        for (int i = tid; i < nb; i += 512)
            gbase[i] = cnt[i] ? atomicAdd(&gc[i * PADI], cnt[i]) : 0;
        __syncthreads();
        // LDS bin-sort scatter (COO re-read, L2-hot)
        for (int i = tid; i < jn; i += 512) {
            const int e = eidx[j0 + i], n = nidx[j0 + i];
            const int b = s ? (n >> 7) : (e >> 5);
            const unsigned pk = s ? (unsigned)(((n & 127) << 15) | e)
                                  : (unsigned)(((e & 31) << 17) | n);
            const int pos = atomicAdd(&cur[b], 1);
            srt[pos] = (int)(pk | ((unsigned)b << 22));
        }
        __syncthreads();
        // ordered write-out: contiguous run per bucket (write-combined)
        for (int i = tid; i < jn; i += 512) {
            const unsigned v = (unsigned)srt[i];
            const int b = v >> 22;
            const int o2 = gbase[b] + (i - lbase[b]);
            if (o2 < cap) dst[b * cap + o2] = (int)(v & 0x3FFFFFu);
        }
        __syncthreads();
    }
}

// ---------------------------------------------------------------------------
// Kernel 2: edge mean. Block = 32-edge bucket, 512 threads. Counting-sort in
// LDS, then 32 x 16-lane groups gather xb rows; s = bf16(mean).
// ---------------------------------------------------------------------------
__global__ __launch_bounds__(512) void edge_mean(
    const int* __restrict__ bucket_e, const int* __restrict__ gcur_e,
    const unsigned short* __restrict__ xb, unsigned short* __restrict__ sb) {
    __shared__ int raw[ECAP];
    __shared__ int srt[ECAP];
    __shared__ int cnt[EBW + 1];
    __shared__ int cur[EBW];
    const int tid = threadIdx.x;
    const int b = blockIdx.x;
    int W = gcur_e[b * PADI];
    if (W > ECAP) W = ECAP;
    if (tid <= EBW) cnt[tid] = 0;
    __syncthreads();
    const int* src = bucket_e + b * ECAP;
    for (int i = tid; i < W; i += 512) {
        const int p = src[i];
        raw[i] = p;
        atomicAdd(&cnt[p >> 17], 1);
    }
    __syncthreads();
    if (tid < EBW) {        // wave-0 exclusive scan over 32 bins
        const int c = cnt[tid];
        int v = c;
#pragma unroll
        for (int off = 1; off < EBW; off <<= 1) {
            const int t = __shfl_up(v, off);
            if (tid >= off) v += t;
        }
        cnt[tid] = v - c;
        cur[tid] = v - c;
        if (tid == EBW - 1) cnt[EBW] = v;
    }
    __syncthreads();
    for (int i = tid; i < W; i += 512) {
        const int p = raw[i];
        const int pos = atomicAdd(&cur[p >> 17], 1);
        srt[pos] = p & 0x1FFFF;
    }
    __syncthreads();

    const int g = tid >> 4;       // 32 groups, 1 edge each
    const int l = tid & 15;       // lane = 8 cols (16B)
    const int beg = cnt[g], end = cnt[g + 1];
    float acc[8] = {};
    int j = beg;
    for (; j + 4 <= end; j += 4) {
        const int n0 = srt[j], n1 = srt[j + 1];
        const int n2 = srt[j + 2], n3 = srt[j + 3];
        const bf16x8 p0 = *(const bf16x8*)(xb + (size_t)n0 * D + l * 8);
        const bf16x8 p1 = *(const bf16x8*)(xb + (size_t)n1 * D + l * 8);
        const bf16x8 p2 = *(const bf16x8*)(xb + (size_t)n2 * D + l * 8);
        const bf16x8 p3 = *(const bf16x8*)(xb + (size_t)n3 * D + l * 8);
#pragma unroll
        for (int i = 0; i < 8; ++i)
            acc[i] += (bf2f((unsigned short)p0[i]) + bf2f((unsigned short)p1[i]))
                    + (bf2f((unsigned short)p2[i]) + bf2f((unsigned short)p3[i]));
    }
    for (; j < end; ++j) {
        const bf16x8 p = *(const bf16x8*)(xb + (size_t)srt[j] * D + l * 8);
#pragma unroll
        for (int i = 0; i < 8; ++i) acc[i] += bf2f((unsigned short)p[i]);
    }
    const int deg = end - beg;
    const float inv = deg ? 1.f / (float)deg : 0.f;
    bf16x8 o;
#pragma unroll
    for (int i = 0; i < 8; ++i) o[i] = (short)f2bf(acc[i] * inv);
    *(bf16x8*)(sb + (size_t)(b * EBW + g) * D + l * 8) = o;   // 625*32 = 20000
}

// ---------------------------------------------------------------------------
// Kernel 3: node mean. Block = 128-node bucket, 512 threads. Counting-sort,
// wave-0 scan (2 bins/lane), 32 groups x 4 nodes gather s rows; z = bf16(mean).
// ---------------------------------------------------------------------------
__global__ __launch_bounds__(512) void node_mean(
    const int* __restrict__ bucket_n, const int* __restrict__ gcur_n,
    const unsigned short* __restrict__ sb, unsigned short* __restrict__ zb) {
    __shared__ int raw[NCAP];
    __shared__ int srt[NCAP];
    __shared__ int cnt[NBW + 1];
    __shared__ int cur[NBW];
    const int tid = threadIdx.x;
    const int b = blockIdx.x;
    int W = gcur_n[b * PADI];
    if (W > NCAP) W = NCAP;
    if (tid <= NBW) cnt[tid] = 0;
    __syncthreads();
    const int* src = bucket_n + b * NCAP;
    for (int i = tid; i < W; i += 512) {
        const int p = src[i];
        raw[i] = p;
        atomicAdd(&cnt[p >> 15], 1);
    }
    __syncthreads();
    if (tid < 64) {          // wave-0 scan, 2 bins per lane (128 bins)
        const int a0 = cnt[tid * 2], a1 = cnt[tid * 2 + 1];
        const int ssum = a0 + a1;
        int v = ssum;
#pragma unroll
        for (int off = 1; off < 64; off <<= 1) {
            const int t = __shfl_up(v, off);
            if (tid >= off) v += t;
        }
        const int base = v - ssum;
        cnt[tid * 2] = base;     cur[tid * 2] = base;
        cnt[tid * 2 + 1] = base + a0; cur[tid * 2 + 1] = base + a0;
        if (tid == 63) cnt[NBW] = v;
    }
    __syncthreads();
    for (int i = tid; i < W; i += 512) {
        const int p = raw[i];
        const int pos = atomicAdd(&cur[p >> 15], 1);
        srt[pos] = p & 0x7FFF;
    }
    __syncthreads();

    const int g = tid >> 4;       // 32 groups, 4 nodes each
    const int l = tid & 15;
#pragma unroll
    for (int u = 0; u < 4; ++u) {
        const int nl = g * 4 + u;
        const int n = b * NBW + nl;
        if (n >= N_NODES) continue;
        const int beg = cnt[nl], end = cnt[nl + 1];
        float acc[8] = {};
        int j = beg;
        for (; j + 2 <= end; j += 2) {
            const int e0 = srt[j], e1 = srt[j + 1];
            const bf16x8 p0 = *(const bf16x8*)(sb + (size_t)e0 * D + l * 8);
            const bf16x8 p1 = *(const bf16x8*)(sb + (size_t)e1 * D + l * 8);
#pragma unroll
            for (int i = 0; i < 8; ++i)
                acc[i] += bf2f((unsigned short)p0[i]) + bf2f((unsigned short)p1[i]);
        }
        if (j < end) {
            const bf16x8 p = *(const bf16x8*)(sb + (size_t)srt[j] * D + l * 8);
#pragma unroll
            for (int i = 0; i < 8; ++i) acc[i] += bf2f((unsigned short)p[i]);
        }
        const int deg = end - beg;
        const float inv = deg ? 1.f / (float)deg : 0.f;
        bf16x8 o;
#pragma unroll
        for (int i = 0; i < 8; ++i) o[i] = (short)f2bf(acc[i] * inv);
        *(bf16x8*)(zb + (size_t)n * D + l * 8) = o;
    }
}

// ---------------------------------------------------------------------------
// Kernel 4: final dual GEMM. out = z@cW + xb@rW + (cb+rb). 8 waves x 16 cols,
// W fragments read directly from fp32, 3 tiles/block, fp32 out (sole writer).
// ---------------------------------------------------------------------------
__global__ __launch_bounds__(512) void final_gemm(
    const unsigned short* __restrict__ zb, const unsigned short* __restrict__ xb,
    const float* __restrict__ cW, const float* __restrict__ rW,
    const float* __restrict__ cbias, const float* __restrict__ rbias,
    float* __restrict__ out) {
    __shared__ unsigned short zs[GT * XPAD];
    __shared__ unsigned short xs[GT * XPAD];

    const int tid  = threadIdx.x;
    const int w    = tid >> 6;
    const int lane = tid & 63;
    const int quad = lane >> 4;
    const int l16  = lane & 15;
    const int f0   = w * 16;          // 16 output cols per wave

    // W fragments (f = f0 + l16), read 64B-coalesced across l16
    const int f = f0 + l16;
    bf16x8 Ac[4], Ar[4];
#pragma unroll
    for (int kc = 0; kc < 4; ++kc)
#pragma unroll
        for (int u = 0; u < 8; ++u) {
            const int k = kc * 32 + quad * 8 + u;
            Ac[kc][u] = (short)f2bf(cW[(size_t)k * D + f]);
            Ar[kc][u] = (short)f2bf(rW[(size_t)k * D + f]);
        }
    // bias for this lane's 4 cols
    const float4 cb4 = *(const float4*)(cbias + f0 + quad * 4);
    const float4 rb4 = *(const float4*)(rbias + f0 + quad * 4);
    const float4 bias = {cb4.x + rb4.x, cb4.y + rb4.y,
                         cb4.z + rb4.z, cb4.w + rb4.w};

    const int r0 = tid >> 3;
    const int qp = tid & 7;

    for (int tt = 0; tt < TPB; ++tt) {
        const int t = blockIdx.x * TPB + tt;
        if (t >= NTILES) break;
        __syncthreads();
        // stage z & xb tiles (pure bf16 copies, 32 B/thread each)
        {
            int n = t * GT + r0;
            if (n >= N_NODES) n = N_NODES - 1;
            const uint4* sz = (const uint4*)(zb + (size_t)n * D + qp * 16);
            const uint4* sx = (const uint4*)(xb + (size_t)n * D + qp * 16);
            uint4* dz = (uint4*)(zs + r0 * XPAD + qp * 16);
            uint4* dx = (uint4*)(xs + r0 * XPAD + qp * 16);
            dz[0] = sz[0]; dz[1] = sz[1];
            dx[0] = sx[0]; dx[1] = sx[1];
        }
        __syncthreads();
        f32x4 acc[4] = {};
#pragma unroll
        for (int g = 0; g < 4; ++g)
#pragma unroll
            for (int kc = 0; kc < 4; ++kc) {
                const int ro = (g * 16 + l16) * XPAD + kc * 32 + quad * 8;
                const bf16x8 Bz = *(const bf16x8*)(zs + ro);
                const bf16x8 Bx = *(const bf16x8*)(xs + ro);
                acc[g] = __builtin_amdgcn_mfma_f32_16x16x32_bf16(Ac[kc], Bz, acc[g], 0, 0, 0);
                acc[g] = __builtin_amdgcn_mfma_f32_16x16x32_bf16(Ar[kc], Bx, acc[g], 0, 0, 0);
            }
        const int nbase = t * GT;
#pragma unroll
        for (int g = 0; g < 4; ++g) {
            const int n = nbase + g * 16 + l16;
            if (n >= N_NODES) continue;
            float4 o;
            o.x = acc[g][0] + bias.x;
            o.y = acc[g][1] + bias.y;
            o.z = acc[g][2] + bias.z;
            o.w = acc[g][3] + bias.w;
            *(float4*)(out + (size_t)n * D + f0 + quad * 4) = o;
        }
    }
}

// ---------------------------------------------------------------------------
extern "C" void kernel_launch(void* const* d_in, const int* in_sizes, int n_in,
                              void* d_out, int out_size, void* d_ws,
                              size_t ws_size, hipStream_t stream) {
    const float* x  = (const float*)d_in[0];
    const int* nidx = (const int*)d_in[1];
    const int* eidx = (const int*)d_in[2];
    const float* cW = (const float*)d_in[3];
    const float* cb = (const float*)d_in[4];
    const float* rW = (const float*)d_in[5];
    const float* rb = (const float*)d_in[6];
    float* out = (float*)d_out;

    char* ws = (char*)d_ws;
    size_t off = 0;
    auto alloc = [&](size_t bytes) {
        size_t o = off;
        off += (bytes + 255) & ~(size_t)255;
        return o;
    };
    unsigned short* xb = (unsigned short*)(ws + alloc((size_t)N_NODES * D * 2));
    unsigned short* sb = (unsigned short*)(ws + alloc((size_t)N_EDGES * D * 2));
    unsigned short* zb = (unsigned short*)(ws + alloc((size_t)N_NODES * D * 2));
    int* bucket_e = (int*)(ws + alloc((size_t)NBE * ECAP * 4));
    int* bucket_n = (int*)(ws + alloc((size_t)NBN * NCAP * 4));
    int* gcur     = (int*)(ws + alloc((size_t)GCUR_INTS * 4));
    int* gcur_e = gcur;
    int* gcur_n = gcur + NBE * PADI;

    hipMemsetAsync(gcur, 0, (size_t)GCUR_INTS * 4, stream);

    fused_bin_conv<<<NCHUNK + CONVB, 512, 0, stream>>>(
        x, nidx, eidx, xb, bucket_e, bucket_n, gcur_e, gcur_n);

    edge_mean<<<NBE, 512, 0, stream>>>(bucket_e, gcur_e, xb, sb);
    node_mean<<<NBN, 512, 0, stream>>>(bucket_n, gcur_n, sb, zb);
    final_gemm<<<GEMM_BLKS, 512, 0, stream>>>(zb, xb, cW, rW, cb, rb, out);
}

// Round 7
// 190.713 us; speedup vs baseline: 1.8210x; 1.0134x over previous
//
#include <hip/hip_runtime.h>

#define N_NODES 100000
#define N_EDGES 20000
#define NNZ_C   600000
#define D 128

typedef short bf16x8 __attribute__((ext_vector_type(8)));
typedef float f32x4  __attribute__((ext_vector_type(4)));

__device__ __forceinline__ unsigned short f2bf(float f) {
    unsigned int u = __float_as_uint(f);
    u = (u + 0x7fffu + ((u >> 16) & 1u)) >> 16;   // RNE
    return (unsigned short)u;
}
__device__ __forceinline__ float bf2f(unsigned short h) {
    return __uint_as_float((unsigned int)h << 16);
}
// pack two fp32 -> two bf16 (truncation) in one v_perm_b32
__device__ __forceinline__ unsigned int pk_trunc(float lo, float hi) {
    return __builtin_amdgcn_perm(__float_as_uint(hi), __float_as_uint(lo),
                                 0x07060302);
}

// ---------------------------------------------------------------------------
// Math plan (linearity): out = (D^-1 H B^-1 H^T xb) @ cW + xb @ rW + (cb+rb)
//   1. fused_bin_conv : bucket COO (write-combined) + xb = bf16(x)
//   2. edge_mean      : s_e = mean_{n in e} xb[n]        (sort-in-LDS gather)
//   3. node_gemm      : z tile (LDS) = mean_{e at n} s[e]; then
//                       out = z@cW + xb@rW + biases      (sole out writer)
// ---------------------------------------------------------------------------
#define CH 4096
#define NCHUNK 147            // ceil(600000/4096)
#define CONVB 256             // x->bf16 convert blocks (grid-stride)
#define EBW 32                // edges per bucket
#define NBE 625               // 20000/32 exact
#define ECAP 1280             // mean 960, sigma 31 -> +10.3σ
#define NBW 128               // nodes per bucket
#define NBN 782               // ceil(100000/128)
#define NCAP 1024             // mean 768, sigma 27.7 -> +9.2σ
#define PADI 32               // ints per counter line (128 B)
#define GCUR_INTS ((NBE + NBN) * PADI)

#define GT 64
#define XPAD 136
#define NTILES ((N_NODES + GT - 1) / GT)   // 1563

// ---------------------------------------------------------------------------
// Kernel 1: blocks [0,147) bin the COO; blocks [147,403) convert x -> bf16.
// Bin role: histogram (global re-read) -> wave0 scan -> parallel base claim
// on line-padded counters -> LDS bin-sort -> contiguous run write-out.
// Bucket id rides in bits 22..31 of the packed value (stripped on write).
// ---------------------------------------------------------------------------
__global__ __launch_bounds__(512) void fused_bin_conv(
    const float* __restrict__ x,
    const int* __restrict__ nidx, const int* __restrict__ eidx,
    unsigned short* __restrict__ xb,
    int* __restrict__ bucket_e, int* __restrict__ bucket_n,
    int* __restrict__ gcur_e, int* __restrict__ gcur_n) {
    __shared__ int srt[CH];
    __shared__ int cnt[NBN], lbase[NBN], gbase[NBN], cur[NBN];
    const int bid = blockIdx.x;
    const int tid = threadIdx.x;

    if (bid >= NCHUNK) {
        // -------- convert role: xb = bf16(x), grid-stride over 8-elt groups
        const int total8 = N_NODES * D / 8;           // 1.6M
        for (int g = (bid - NCHUNK) * 512 + tid; g < total8;
             g += CONVB * 512) {
            const float4 a = *(const float4*)(x + (size_t)g * 8);
            const float4 c = *(const float4*)(x + (size_t)g * 8 + 4);
            uint4 v;
            v.x = pk_trunc(a.x, a.y);
            v.y = pk_trunc(a.z, a.w);
            v.z = pk_trunc(c.x, c.y);
            v.w = pk_trunc(c.z, c.w);
            *(uint4*)(xb + (size_t)g * 8) = v;
        }
        return;
    }

    // -------- bin role
    const int j0 = bid * CH;
    const int jn = (j0 + CH < NNZ_C) ? CH : NNZ_C - j0;
#pragma unroll
    for (int s = 0; s < 2; ++s) {
        const int nb = s ? NBN : NBE;
        int* gc = s ? gcur_n : gcur_e;
        int* dst = s ? bucket_n : bucket_e;
        const int cap = s ? NCAP : ECAP;
        for (int i = tid; i < nb; i += 512) cnt[i] = 0;
        __syncthreads();
        for (int i = tid; i < jn; i += 512) {
            const int id = s ? nidx[j0 + i] : eidx[j0 + i];
            atomicAdd(&cnt[s ? (id >> 7) : (id >> 5)], 1);
        }
        __syncthreads();
        // wave-0 scan: 13 bins/lane covers 782
        if (tid < 64) {
            int loc[13];
            int ssum = 0;
            const int k0 = tid * 13;
#pragma unroll
            for (int k = 0; k < 13; ++k) {
                const int idx = k0 + k;
                loc[k] = ssum;
                if (idx < nb) ssum += cnt[idx];
            }
            int v = ssum;
#pragma unroll
            for (int off = 1; off < 64; off <<= 1) {
                const int t = __shfl_up(v, off);
                if (tid >= off) v += t;
            }
            const int base = v - ssum;
#pragma unroll
            for (int k = 0; k < 13; ++k) {
                const int idx = k0 + k;
                if (idx < nb) {
                    lbase[idx] = base + loc[k];
                    cur[idx] = base + loc[k];
                }
            }
        }
        __syncthreads();
        // parallel per-bucket global base claim (padded counters)
        for (int i = tid; i < nb; i += 512)
            gbase[i] = cnt[i] ? atomicAdd(&gc[i * PADI], cnt[i]) : 0;
        __syncthreads();
        // LDS bin-sort scatter (COO re-read, L2-hot)
        for (int i = tid; i < jn; i += 512) {
            const int e = eidx[j0 + i], n = nidx[j0 + i];
            const int b = s ? (n >> 7) : (e >> 5);
            const unsigned pk = s ? (unsigned)(((n & 127) << 15) | e)
                                  : (unsigned)(((e & 31) << 17) | n);
            const int pos = atomicAdd(&cur[b], 1);
            srt[pos] = (int)(pk | ((unsigned)b << 22));
        }
        __syncthreads();
        // ordered write-out: contiguous run per bucket (write-combined)
        for (int i = tid; i < jn; i += 512) {
            const unsigned v = (unsigned)srt[i];
            const int b = v >> 22;
            const int o2 = gbase[b] + (i - lbase[b]);
            if (o2 < cap) dst[b * cap + o2] = (int)(v & 0x3FFFFFu);
        }
        __syncthreads();
    }
}

// ---------------------------------------------------------------------------
// Kernel 2: edge mean. Block = 32-edge bucket, 512 threads. Counting-sort in
// LDS, then 32 x 16-lane groups gather xb rows; s = bf16(mean). 8-deep
// unrolled gather for more loads in flight.
// ---------------------------------------------------------------------------
__global__ __launch_bounds__(512) void edge_mean(
    const int* __restrict__ bucket_e, const int* __restrict__ gcur_e,
    const unsigned short* __restrict__ xb, unsigned short* __restrict__ sb) {
    __shared__ int raw[ECAP];
    __shared__ int srt[ECAP];
    __shared__ int cnt[EBW + 1];
    __shared__ int cur[EBW];
    const int tid = threadIdx.x;
    const int b = blockIdx.x;
    int W = gcur_e[b * PADI];
    if (W > ECAP) W = ECAP;
    if (tid <= EBW) cnt[tid] = 0;
    __syncthreads();
    const int* src = bucket_e + b * ECAP;
    for (int i = tid; i < W; i += 512) {
        const int p = src[i];
        raw[i] = p;
        atomicAdd(&cnt[p >> 17], 1);
    }
    __syncthreads();
    if (tid < EBW) {        // wave-0 exclusive scan over 32 bins
        const int c = cnt[tid];
        int v = c;
#pragma unroll
        for (int off = 1; off < EBW; off <<= 1) {
            const int t = __shfl_up(v, off);
            if (tid >= off) v += t;
        }
        cnt[tid] = v - c;
        cur[tid] = v - c;
        if (tid == EBW - 1) cnt[EBW] = v;
    }
    __syncthreads();
    for (int i = tid; i < W; i += 512) {
        const int p = raw[i];
        const int pos = atomicAdd(&cur[p >> 17], 1);
        srt[pos] = p & 0x1FFFF;
    }
    __syncthreads();

    const int g = tid >> 4;       // 32 groups, 1 edge each
    const int l = tid & 15;       // lane = 8 cols (16B)
    const int beg = cnt[g], end = cnt[g + 1];
    float acc[8] = {};
    int j = beg;
    for (; j + 8 <= end; j += 8) {
        bf16x8 p[8];
#pragma unroll
        for (int q = 0; q < 8; ++q)
            p[q] = *(const bf16x8*)(xb + (size_t)srt[j + q] * D + l * 8);
#pragma unroll
        for (int i = 0; i < 8; ++i) {
            float t0 = bf2f((unsigned short)p[0][i]) + bf2f((unsigned short)p[1][i]);
            float t1 = bf2f((unsigned short)p[2][i]) + bf2f((unsigned short)p[3][i]);
            float t2 = bf2f((unsigned short)p[4][i]) + bf2f((unsigned short)p[5][i]);
            float t3 = bf2f((unsigned short)p[6][i]) + bf2f((unsigned short)p[7][i]);
            acc[i] += (t0 + t1) + (t2 + t3);
        }
    }
    for (; j + 4 <= end; j += 4) {
        const int n0 = srt[j], n1 = srt[j + 1];
        const int n2 = srt[j + 2], n3 = srt[j + 3];
        const bf16x8 p0 = *(const bf16x8*)(xb + (size_t)n0 * D + l * 8);
        const bf16x8 p1 = *(const bf16x8*)(xb + (size_t)n1 * D + l * 8);
        const bf16x8 p2 = *(const bf16x8*)(xb + (size_t)n2 * D + l * 8);
        const bf16x8 p3 = *(const bf16x8*)(xb + (size_t)n3 * D + l * 8);
#pragma unroll
        for (int i = 0; i < 8; ++i)
            acc[i] += (bf2f((unsigned short)p0[i]) + bf2f((unsigned short)p1[i]))
                    + (bf2f((unsigned short)p2[i]) + bf2f((unsigned short)p3[i]));
    }
    for (; j < end; ++j) {
        const bf16x8 p = *(const bf16x8*)(xb + (size_t)srt[j] * D + l * 8);
#pragma unroll
        for (int i = 0; i < 8; ++i) acc[i] += bf2f((unsigned short)p[i]);
    }
    const int deg = end - beg;
    const float inv = deg ? 1.f / (float)deg : 0.f;
    bf16x8 o;
#pragma unroll
    for (int i = 0; i < 8; ++i) o[i] = (short)f2bf(acc[i] * inv);
    *(bf16x8*)(sb + (size_t)(b * EBW + g) * D + l * 8) = o;   // 625*32 = 20000
}

// ---------------------------------------------------------------------------
// Kernel 3: node mean + dual GEMM, fused. Block = 128-node bucket = two
// 64-row GEMM tiles. Sort bucket, gather s rows -> z tile in LDS (bf16;
// empty/invalid nodes yield zeros), then out = z@cW + xb@rW + (cb+rb).
// ---------------------------------------------------------------------------
__global__ __launch_bounds__(512, 4) void node_gemm(
    const int* __restrict__ bucket_n, const int* __restrict__ gcur_n,
    const unsigned short* __restrict__ sb, const unsigned short* __restrict__ xb,
    const float* __restrict__ cW, const float* __restrict__ rW,
    const float* __restrict__ cbias, const float* __restrict__ rbias,
    float* __restrict__ out) {
    __shared__ int raw[NCAP];
    __shared__ int srt[NCAP];
    __shared__ int cnt[NBW + 1];
    __shared__ int cur[NBW];
    __shared__ unsigned short zs[NBW * XPAD];   // 128-row z tile (34.8 KB)
    __shared__ unsigned short xs[GT * XPAD];    // 64-row x tile (17.4 KB)
    const int tid = threadIdx.x;
    const int b = blockIdx.x;

    // ---- counting sort of the bucket by local node id ----
    int W = gcur_n[b * PADI];
    if (W > NCAP) W = NCAP;
    if (tid <= NBW) cnt[tid] = 0;
    __syncthreads();
    const int* src = bucket_n + b * NCAP;
    for (int i = tid; i < W; i += 512) {
        const int p = src[i];
        raw[i] = p;
        atomicAdd(&cnt[p >> 15], 1);
    }
    __syncthreads();
    if (tid < 64) {          // wave-0 scan, 2 bins per lane (128 bins)
        const int a0 = cnt[tid * 2], a1 = cnt[tid * 2 + 1];
        const int ssum = a0 + a1;
        int v = ssum;
#pragma unroll
        for (int off = 1; off < 64; off <<= 1) {
            const int t = __shfl_up(v, off);
            if (tid >= off) v += t;
        }
        const int base = v - ssum;
        cnt[tid * 2] = base;          cur[tid * 2] = base;
        cnt[tid * 2 + 1] = base + a0; cur[tid * 2 + 1] = base + a0;
        if (tid == 63) cnt[NBW] = v;
    }
    __syncthreads();
    for (int i = tid; i < W; i += 512) {
        const int p = raw[i];
        const int pos = atomicAdd(&cur[p >> 15], 1);
        srt[pos] = p & 0x7FFF;
    }
    __syncthreads();

    // ---- gather s rows -> z tile rows (bf16 mean; empty rows -> 0) ----
    {
        const int g = tid >> 4;       // 32 groups, 4 nodes each
        const int l = tid & 15;
#pragma unroll
        for (int u = 0; u < 4; ++u) {
            const int nl = g * 4 + u;
            const int beg = cnt[nl], end = cnt[nl + 1];
            float acc[8] = {};
            int j = beg;
            for (; j + 4 <= end; j += 4) {
                const int e0 = srt[j], e1 = srt[j + 1];
                const int e2 = srt[j + 2], e3 = srt[j + 3];
                const bf16x8 p0 = *(const bf16x8*)(sb + (size_t)e0 * D + l * 8);
                const bf16x8 p1 = *(const bf16x8*)(sb + (size_t)e1 * D + l * 8);
                const bf16x8 p2 = *(const bf16x8*)(sb + (size_t)e2 * D + l * 8);
                const bf16x8 p3 = *(const bf16x8*)(sb + (size_t)e3 * D + l * 8);
#pragma unroll
                for (int i = 0; i < 8; ++i)
                    acc[i] += (bf2f((unsigned short)p0[i]) + bf2f((unsigned short)p1[i]))
                            + (bf2f((unsigned short)p2[i]) + bf2f((unsigned short)p3[i]));
            }
            for (; j < end; ++j) {
                const bf16x8 p = *(const bf16x8*)(sb + (size_t)srt[j] * D + l * 8);
#pragma unroll
                for (int i = 0; i < 8; ++i) acc[i] += bf2f((unsigned short)p[i]);
            }
            const int deg = end - beg;
            const float inv = deg ? 1.f / (float)deg : 0.f;
            bf16x8 o;
#pragma unroll
            for (int i = 0; i < 8; ++i) o[i] = (short)f2bf(acc[i] * inv);
            *(bf16x8*)(zs + nl * XPAD + l * 8) = o;
        }
    }

    // ---- W fragments & bias (f = w*16 + l16), read 64B-coalesced ----
    const int w    = tid >> 6;
    const int lane = tid & 63;
    const int quad = lane >> 4;
    const int l16  = lane & 15;
    const int f0   = w * 16;
    const int f    = f0 + l16;
    bf16x8 Ac[4], Ar[4];
#pragma unroll
    for (int kc = 0; kc < 4; ++kc)
#pragma unroll
        for (int u = 0; u < 8; ++u) {
            const int k = kc * 32 + quad * 8 + u;
            Ac[kc][u] = (short)f2bf(cW[(size_t)k * D + f]);
            Ar[kc][u] = (short)f2bf(rW[(size_t)k * D + f]);
        }
    const float4 cb4 = *(const float4*)(cbias + f0 + quad * 4);
    const float4 rb4 = *(const float4*)(rbias + f0 + quad * 4);
    const float4 bias = {cb4.x + rb4.x, cb4.y + rb4.y,
                         cb4.z + rb4.z, cb4.w + rb4.w};

    const int r0 = tid >> 3;
    const int qp = tid & 7;

    // ---- two 64-row halves: stage xb tile, dual MFMA, write out ----
#pragma unroll
    for (int h = 0; h < 2; ++h) {
        __syncthreads();   // h=0: z tile complete; h=1: xs reads of h=0 done
        {
            int n = b * NBW + h * GT + r0;
            if (n >= N_NODES) n = N_NODES - 1;
            const uint4* sx = (const uint4*)(xb + (size_t)n * D + qp * 16);
            uint4* dx = (uint4*)(xs + r0 * XPAD + qp * 16);
            dx[0] = sx[0]; dx[1] = sx[1];
        }
        __syncthreads();
        f32x4 acc[4] = {};
#pragma unroll
        for (int g = 0; g < 4; ++g)
#pragma unroll
            for (int kc = 0; kc < 4; ++kc) {
                const int ko = kc * 32 + quad * 8;
                const bf16x8 Bz = *(const bf16x8*)(zs + (h * GT + g * 16 + l16) * XPAD + ko);
                const bf16x8 Bx = *(const bf16x8*)(xs + (g * 16 + l16) * XPAD + ko);
                acc[g] = __builtin_amdgcn_mfma_f32_16x16x32_bf16(Ac[kc], Bz, acc[g], 0, 0, 0);
                acc[g] = __builtin_amdgcn_mfma_f32_16x16x32_bf16(Ar[kc], Bx, acc[g], 0, 0, 0);
            }
#pragma unroll
        for (int g = 0; g < 4; ++g) {
            const int n = b * NBW + h * GT + g * 16 + l16;
            if (n >= N_NODES) continue;
            float4 o;
            o.x = acc[g][0] + bias.x;
            o.y = acc[g][1] + bias.y;
            o.z = acc[g][2] + bias.z;
            o.w = acc[g][3] + bias.w;
            *(float4*)(out + (size_t)n * D + f0 + quad * 4) = o;
        }
    }
}

// ---------------------------------------------------------------------------
extern "C" void kernel_launch(void* const* d_in, const int* in_sizes, int n_in,
                              void* d_out, int out_size, void* d_ws,
                              size_t ws_size, hipStream_t stream) {
    const float* x  = (const float*)d_in[0];
    const int* nidx = (const int*)d_in[1];
    const int* eidx = (const int*)d_in[2];
    const float* cW = (const float*)d_in[3];
    const float* cb = (const float*)d_in[4];
    const float* rW = (const float*)d_in[5];
    const float* rb = (const float*)d_in[6];
    float* out = (float*)d_out;

    char* ws = (char*)d_ws;
    size_t off = 0;
    auto alloc = [&](size_t bytes) {
        size_t o = off;
        off += (bytes + 255) & ~(size_t)255;
        return o;
    };
    unsigned short* xb = (unsigned short*)(ws + alloc((size_t)N_NODES * D * 2));
    unsigned short* sb = (unsigned short*)(ws + alloc((size_t)N_EDGES * D * 2));
    int* bucket_e = (int*)(ws + alloc((size_t)NBE * ECAP * 4));
    int* bucket_n = (int*)(ws + alloc((size_t)NBN * NCAP * 4));
    int* gcur     = (int*)(ws + alloc((size_t)GCUR_INTS * 4));
    int* gcur_e = gcur;
    int* gcur_n = gcur + NBE * PADI;

    hipMemsetAsync(gcur, 0, (size_t)GCUR_INTS * 4, stream);

    fused_bin_conv<<<NCHUNK + CONVB, 512, 0, stream>>>(
        x, nidx, eidx, xb, bucket_e, bucket_n, gcur_e, gcur_n);

    edge_mean<<<NBE, 512, 0, stream>>>(bucket_e, gcur_e, xb, sb);
    node_gemm<<<NBN, 512, 0, stream>>>(bucket_n, gcur_n, sb, xb,
                                       cW, rW, cb, rb, out);
}